// Round 13
// baseline (812.418 us; speedup 1.0000x reference)
//
#include <hip/hip_runtime.h>

#define N_NODES 100000
#define N_EDGES 1600000
#define N_GRAPHS 256
#define EPS 1e-5f

#define NBUCK 1024   // buckets = tgt >> 7
#define NUSED 782

// k_prep block ranges
#define WB 128   // W1/W2 transpose
#define W0B 32   // W0 transpose
#define SB 2     // graph starts
#define HB 512   // histogram blocks (grid-stride)
#define PREP_BLOCKS (WB + W0B + SB + HB)

typedef __attribute__((ext_vector_type(8))) short bfrag8;  // 8 bf16
typedef __attribute__((ext_vector_type(4))) float facc4;   // 4 f32 acc

__device__ __forceinline__ void fma4(float4& a, float s, const float4& w) {
  a.x += s * w.x; a.y += s * w.y; a.z += s * w.z; a.w += s * w.w;
}

__device__ __forceinline__ unsigned short f2bf(float f) {
  union { float f; unsigned u; } x;
  x.f = f;
  unsigned r = x.u + 0x7FFF + ((x.u >> 16) & 1);  // RNE
  return (unsigned short)(r >> 16);
}
__device__ __forceinline__ unsigned packbf(float a, float b) {
  return (unsigned)f2bf(a) | ((unsigned)f2bf(b) << 16);
}
__device__ __forceinline__ float4 bf4(unsigned lo, unsigned hi) {
  union { unsigned u; float f; } a, b, c, d;
  a.u = lo << 16;
  b.u = lo & 0xFFFF0000u;
  c.u = hi << 16;
  d.u = hi & 0xFFFF0000u;
  return make_float4(a.f, b.f, c.f, d.f);
}
__device__ __forceinline__ float bfat(const unsigned* tb, int idx) {
  unsigned u = tb[idx >> 1];
  union { unsigned u; float f; } v;
  v.u = (idx & 1) ? (u & 0xFFFF0000u) : (u << 16);
  return v.f;
}

// ---------------------------------------------------------------------------
// Prep: W transposes, graph starts, bucket histogram (LDS + merge).
// ---------------------------------------------------------------------------
__global__ __launch_bounds__(256) void k_prep(
    const float* __restrict__ cw1, const float* __restrict__ cw2,
    unsigned short* __restrict__ wt1, unsigned short* __restrict__ wt2,
    const float* __restrict__ cw0, unsigned short* __restrict__ wt0,
    const int* __restrict__ batch, int* __restrict__ start,
    const int* __restrict__ tgt, int* __restrict__ bcnt) {
  __shared__ int h[NBUCK];
  const int b = blockIdx.x;
  const int t = threadIdx.x;
  if (b < WB) {
    int half = b >> 6;              // 0: w1, 1: w2
    int id = (b & 63) * 256 + t;    // 0..16383
    const float* w = half ? cw2 : cw1;
    unsigned short* o = half ? wt2 : wt1;
    int n = id >> 7, k = id & 127;
    o[n * 128 + k] = f2bf(w[k * 128 + n]);
  } else if (b < WB + W0B) {
    int id = (b - WB) * 256 + t;
    if (id >= 8192) return;
    int n = id >> 6, k = id & 63;
    wt0[n * 64 + k] = f2bf(cw0[k * 128 + n]);
  } else if (b < WB + W0B + SB) {
    int g = (b - WB - W0B) * 256 + t;
    if (g > N_GRAPHS) return;
    int lo = 0, hi = N_NODES;
    while (lo < hi) {
      int mid = (lo + hi) >> 1;
      if (batch[mid] < g) lo = mid + 1; else hi = mid;
    }
    start[g] = lo;
  } else {
    const int hb = b - WB - W0B - SB;
    for (int i = t; i < NBUCK; i += 256) h[i] = 0;
    __syncthreads();
    for (int j = hb * 256 + t; j < N_EDGES; j += HB * 256)
      atomicAdd(&h[tgt[j] >> 7], 1);
    __syncthreads();
    for (int i = t; i < NBUCK; i += 256) {
      int v = h[i];
      if (v) atomicAdd(&bcnt[i], v);
    }
  }
}

// ---------------------------------------------------------------------------
// Bucket scan: 1 block x 1024 -> bbase (exclusive), gcur copy.
// ---------------------------------------------------------------------------
__global__ __launch_bounds__(1024) void k_bscan(const int* __restrict__ bcnt,
                                                int* __restrict__ bbase,
                                                int* __restrict__ gcur) {
  __shared__ int s[NBUCK];
  const int b = threadIdx.x;
  int v = bcnt[b];
  s[b] = v;
  __syncthreads();
  for (int off = 1; off < NBUCK; off <<= 1) {
    int u = (b >= off) ? s[b - off] : 0;
    __syncthreads();
    s[b] += u;
    __syncthreads();
  }
  int base = s[b] - v;  // exclusive
  bbase[b] = base;
  gcur[b] = base;
  if (b == NBUCK - 1) bbase[NBUCK] = N_EDGES;
}

// ---------------------------------------------------------------------------
// Fused edge-MLP + bucket scatter: computes ew inline from edge_attr,
// global hot-line cursor atomics (1024 counters), writes
// mb[pos] = {bits(ew), src | (tgt&127)<<25}.
// ---------------------------------------------------------------------------
__global__ __launch_bounds__(256) void k_scatter(
    const float* __restrict__ ea, const float* __restrict__ w1,
    const float* __restrict__ b1, const float* __restrict__ w2,
    const float* __restrict__ b2, const int* __restrict__ src,
    const int* __restrict__ tgt, int* __restrict__ gcur,
    uint2* __restrict__ mb) {
  __shared__ float W1[128], B1[16], W2[16];
  const int t = threadIdx.x;
  if (t < 128) W1[t] = w1[t];
  if (t < 16) { B1[t] = b1[t]; W2[t] = w2[t]; }
  __syncthreads();
  int e = blockIdx.x * 256 + t;
  if (e >= N_EDGES) return;
  const float4* ap = (const float4*)(ea + (size_t)e * 8);
  float4 a0 = ap[0], a1 = ap[1];
  float a[8] = {a0.x, a0.y, a0.z, a0.w, a1.x, a1.y, a1.z, a1.w};
  float out = b2[0];
#pragma unroll
  for (int i = 0; i < 16; ++i) {
    float h = B1[i];
#pragma unroll
    for (int j = 0; j < 8; ++j) h += a[j] * W1[i * 8 + j];
    out += fmaxf(h, 0.f) * W2[i];
  }
  int d = tgt[e];
  int pos = atomicAdd(&gcur[d >> 7], 1);
  union { float f; unsigned u; } w;
  w.f = out;
  mb[pos] = make_uint2(w.u, (unsigned)src[e] | ((unsigned)(d & 127) << 25));
}

// ---------------------------------------------------------------------------
// Bucket -> CSR + dinv: one block per bucket. Pass 1 bins counts AND float
// deg sums (LDS atomics); scan -> rowstart + dinv; pass 2 places meta.
// ---------------------------------------------------------------------------
__global__ __launch_bounds__(256) void k_csr(const uint2* __restrict__ mb,
                                             const int* __restrict__ bbase,
                                             uint2* __restrict__ meta,
                                             int* __restrict__ rowstart,
                                             float* __restrict__ dinv) {
  __shared__ int hist[128];
  __shared__ float degf[128];
  __shared__ int cur[128];
  const int b = blockIdx.x;
  const int t = threadIdx.x;
  const int s = bbase[b], e = bbase[b + 1];
  if (t < 128) { hist[t] = 0; degf[t] = 0.f; }
  __syncthreads();
  for (int j = s + t; j < e; j += 256) {
    uint2 m = mb[j];
    int bin = m.y >> 25;
    atomicAdd(&hist[bin], 1);
    union { unsigned u; float f; } w;
    w.u = m.x;
    atomicAdd(&degf[bin], w.f);
  }
  __syncthreads();
  int own = (t < 128) ? hist[t] : 0;
  for (int off = 1; off < 128; off <<= 1) {
    int u = (t >= off && t < 128) ? hist[t - off] : 0;
    __syncthreads();
    if (t < 128) hist[t] += u;
    __syncthreads();
  }
  if (t < 128) {
    int excl = hist[t] - own;
    int node = b * 128 + t;
    if (node <= N_NODES) rowstart[node] = s + excl;
    if (node < N_NODES) {
      float d = 1.f + degf[t];
      dinv[node] = d > 0.f ? rsqrtf(d) : 0.f;
    }
    cur[t] = s + excl;
  }
  __syncthreads();
  for (int j = s + t; j < e; j += 256) {
    uint2 m = mb[j];
    int bin = m.y >> 25;
    int pos = atomicAdd(&cur[bin], 1);
    meta[pos] = make_uint2(m.x, m.y & 0x1FFFFFFu);
  }
}

// x (f32) -> xb = bf16(dinv*x), 8 ch/thread
__global__ __launch_bounds__(256) void k_cvt(const float* __restrict__ x,
                                             const float* __restrict__ dinv,
                                             unsigned* __restrict__ xb) {
  int i = blockIdx.x * 256 + threadIdx.x;
  if (i >= N_NODES * 8) return;
  int n = i >> 3;
  float dv = dinv[n];
  const float4* p = (const float4*)(x + (size_t)i * 8);
  float4 a = p[0], b = p[1];
  uint4 o;
  o.x = packbf(dv * a.x, dv * a.y);
  o.y = packbf(dv * a.z, dv * a.w);
  o.z = packbf(dv * b.x, dv * b.y);
  o.w = packbf(dv * b.z, dv * b.w);
  ((uint4*)xb)[i] = o;
}

// ---------------------------------------------------------------------------
// 64-ch CSR gather on pre-scaled bf16 x' (= dinv*x).
// ---------------------------------------------------------------------------
__global__ __launch_bounds__(256) void k_gather64b(
    const unsigned* __restrict__ xb, const uint2* __restrict__ meta,
    const int* __restrict__ rowstart, const float* __restrict__ dinv,
    unsigned* __restrict__ aggxb) {
  const int t = threadIdx.x;
  const int n = blockIdx.x * 4 + (t >> 6);
  if (n >= N_NODES) return;
  const unsigned lane = t & 63;
  const unsigned q = lane >> 3;   // edge slot 0..7
  const unsigned cl = lane & 7;   // uint4 group (8 ch) over 64 ch
  const int rs = rowstart[n], re = rowstart[n + 1];
  const uint4* x4 = (const uint4*)xb;
  float4 lo0 = make_float4(0.f, 0.f, 0.f, 0.f), hi0 = lo0;
  float4 lo1 = lo0, hi1 = lo0;
  int j = rs;
  for (; j + 16 <= re; j += 16) {
    uint2 m0 = meta[j + q], m1 = meta[j + 8 + q];
    union { unsigned u; float f; } w0, w1;
    w0.u = m0.x; w1.u = m1.x;
    uint4 v0 = x4[(m0.y << 3) + cl];
    uint4 v1 = x4[(m1.y << 3) + cl];
    fma4(lo0, w0.f, bf4(v0.x, v0.y));
    fma4(hi0, w0.f, bf4(v0.z, v0.w));
    fma4(lo1, w1.f, bf4(v1.x, v1.y));
    fma4(hi1, w1.f, bf4(v1.z, v1.w));
  }
  for (; j + 8 <= re; j += 8) {
    uint2 m0 = meta[j + q];
    union { unsigned u; float f; } w0;
    w0.u = m0.x;
    uint4 v0 = x4[(m0.y << 3) + cl];
    fma4(lo0, w0.f, bf4(v0.x, v0.y));
    fma4(hi0, w0.f, bf4(v0.z, v0.w));
  }
  if (j + (int)q < re) {
    uint2 m0 = meta[j + q];
    union { unsigned u; float f; } w0;
    w0.u = m0.x;
    uint4 v0 = x4[(m0.y << 3) + cl];
    fma4(lo1, w0.f, bf4(v0.x, v0.y));
    fma4(hi1, w0.f, bf4(v0.z, v0.w));
  }
  lo0.x += lo1.x; lo0.y += lo1.y; lo0.z += lo1.z; lo0.w += lo1.w;
  hi0.x += hi1.x; hi0.y += hi1.y; hi0.z += hi1.z; hi0.w += hi1.w;
#pragma unroll
  for (int m = 8; m <= 32; m <<= 1) {
    lo0.x += __shfl_xor(lo0.x, m);
    lo0.y += __shfl_xor(lo0.y, m);
    lo0.z += __shfl_xor(lo0.z, m);
    lo0.w += __shfl_xor(lo0.w, m);
    hi0.x += __shfl_xor(hi0.x, m);
    hi0.y += __shfl_xor(hi0.y, m);
    hi0.z += __shfl_xor(hi0.z, m);
    hi0.w += __shfl_xor(hi0.w, m);
  }
  if (q == 0) {
    float dv = dinv[n];
    uint4 sv = x4[((unsigned)n << 3) + cl];
    float4 slo = bf4(sv.x, sv.y), shi = bf4(sv.z, sv.w);
    uint4 o;
    o.x = packbf(dv * (lo0.x + slo.x), dv * (lo0.y + slo.y));
    o.y = packbf(dv * (lo0.z + slo.z), dv * (lo0.w + slo.w));
    o.z = packbf(dv * (hi0.x + shi.x), dv * (hi0.y + shi.y));
    o.w = packbf(dv * (hi0.z + shi.z), dv * (hi0.w + shi.w));
    ((uint4*)aggxb)[((unsigned)n << 3) + cl] = o;
  }
}

// ---------------------------------------------------------------------------
// Layer-0 MFMA GEMM: h1b = bf16( aggxb @ W0 + b0 ).  CIN=64.
// ---------------------------------------------------------------------------
__global__ __launch_bounds__(256) void k_hw_mfma0(
    const unsigned short* __restrict__ aggxb,
    const unsigned short* __restrict__ wt0, const float* __restrict__ bias,
    unsigned short* __restrict__ h1b) {
  __shared__ unsigned short Asb[64][72];
  __shared__ unsigned short Wsb[128][72];
  const int t = threadIdx.x;
  const int base = blockIdx.x * 64;

  for (int i = t; i < 1024; i += 256) {
    int nr = i >> 3, k8 = (i & 7) * 8;
    *(uint4*)&Wsb[nr][k8] = *(const uint4*)&wt0[nr * 64 + k8];
  }
  {
    const int ln = t >> 2;
    const int kp = (t & 3) * 16;
    const int n = base + ln;
    if (n < N_NODES) {
      *(uint4*)&Asb[ln][kp] = *(const uint4*)&aggxb[(size_t)n * 64 + kp];
      *(uint4*)&Asb[ln][kp + 8] = *(const uint4*)&aggxb[(size_t)n * 64 + kp + 8];
    } else {
      uint4 z = make_uint4(0, 0, 0, 0);
      *(uint4*)&Asb[ln][kp] = z;
      *(uint4*)&Asb[ln][kp + 8] = z;
    }
  }
  __syncthreads();

  const int wv = t >> 6;
  const int lr = t & 15;
  const int lk = (t >> 4) & 3;
  const int m0 = wv * 16;

  bfrag8 af[2];
#pragma unroll
  for (int kc = 0; kc < 2; ++kc)
    af[kc] = *(const bfrag8*)&Asb[m0 + lr][kc * 32 + lk * 8];

#pragma unroll
  for (int nt = 0; nt < 8; ++nt) {
    facc4 c = {0.f, 0.f, 0.f, 0.f};
#pragma unroll
    for (int kc = 0; kc < 2; ++kc) {
      bfrag8 bf = *(const bfrag8*)&Wsb[nt * 16 + lr][kc * 32 + lk * 8];
      c = __builtin_amdgcn_mfma_f32_16x16x32_bf16(af[kc], bf, c, 0, 0, 0);
    }
    int col = nt * 16 + lr;
    float bv = bias[col];
#pragma unroll
    for (int r = 0; r < 4; ++r) {
      int n = base + m0 + lk * 4 + r;
      if (n < N_NODES) h1b[(size_t)n * 128 + col] = f2bf(c[r] + bv);
    }
  }
}

// ---------------------------------------------------------------------------
// Layers 1-2 MFMA GEMM: hwb = bf16( dinv[n] * (relu(A*h+B) @ W) ).
// ---------------------------------------------------------------------------
__global__ __launch_bounds__(256) void k_hw_mfma(
    const unsigned* __restrict__ hb, const unsigned short* __restrict__ wt,
    const int* __restrict__ batch, const float* __restrict__ An,
    const float* __restrict__ Bn, const float* __restrict__ dinv,
    unsigned short* __restrict__ hwb) {
  __shared__ unsigned short Asb[64][136];
  __shared__ unsigned short Wsb[128][136];
  const int t = threadIdx.x;
  const int base = blockIdx.x * 64;

  for (int i = t; i < 2048; i += 256) {
    int nr = i >> 4, k8 = (i & 15) * 8;
    *(uint4*)&Wsb[nr][k8] = *(const uint4*)&wt[nr * 128 + k8];
  }
  {
    const int ln = t >> 2;
    const int cg = (t & 3) * 32;
    const int n = base + ln;
    if (n < N_NODES) {
      const int g = batch[n];
      const uint4* hp = (const uint4*)(hb + (size_t)n * 64);
      const float* Ap = An + (size_t)g * 128;
      const float* Bp = Bn + (size_t)g * 128;
#pragma unroll
      for (int qq = 0; qq < 4; ++qq) {
        int c = cg + qq * 8;
        uint4 v = hp[(t & 3) * 4 + qq];
        float4 lo = bf4(v.x, v.y);
        float4 hi = bf4(v.z, v.w);
        float4 Alo = *(const float4*)&Ap[c], Blo = *(const float4*)&Bp[c];
        float4 Ahi = *(const float4*)&Ap[c + 4], Bhi = *(const float4*)&Bp[c + 4];
        uint4 o;
        o.x = packbf(fmaxf(Alo.x * lo.x + Blo.x, 0.f),
                     fmaxf(Alo.y * lo.y + Blo.y, 0.f));
        o.y = packbf(fmaxf(Alo.z * lo.z + Blo.z, 0.f),
                     fmaxf(Alo.w * lo.w + Blo.w, 0.f));
        o.z = packbf(fmaxf(Ahi.x * hi.x + Bhi.x, 0.f),
                     fmaxf(Ahi.y * hi.y + Bhi.y, 0.f));
        o.w = packbf(fmaxf(Ahi.z * hi.z + Bhi.z, 0.f),
                     fmaxf(Ahi.w * hi.w + Bhi.w, 0.f));
        *(uint4*)&Asb[ln][c] = o;
      }
    } else {
      uint4 z = make_uint4(0, 0, 0, 0);
#pragma unroll
      for (int qq = 0; qq < 4; ++qq) *(uint4*)&Asb[ln][cg + qq * 8] = z;
    }
  }
  __syncthreads();

  const int wv = t >> 6;
  const int lr = t & 15;
  const int lk = (t >> 4) & 3;
  const int m0 = wv * 16;

  bfrag8 af[4];
#pragma unroll
  for (int kc = 0; kc < 4; ++kc)
    af[kc] = *(const bfrag8*)&Asb[m0 + lr][kc * 32 + lk * 8];

  float dv[4];
#pragma unroll
  for (int r = 0; r < 4; ++r) {
    int n = base + m0 + lk * 4 + r;
    dv[r] = (n < N_NODES) ? dinv[n] : 0.f;
  }

#pragma unroll
  for (int nt = 0; nt < 8; ++nt) {
    facc4 c = {0.f, 0.f, 0.f, 0.f};
#pragma unroll
    for (int kc = 0; kc < 4; ++kc) {
      bfrag8 bf = *(const bfrag8*)&Wsb[nt * 16 + lr][kc * 32 + lk * 8];
      c = __builtin_amdgcn_mfma_f32_16x16x32_bf16(af[kc], bf, c, 0, 0, 0);
    }
    int col = nt * 16 + lr;
#pragma unroll
    for (int r = 0; r < 4; ++r) {
      int n = base + m0 + lk * 4 + r;
      if (n < N_NODES) hwb[(size_t)n * 128 + col] = f2bf(dv[r] * c[r]);
    }
  }
}

// ---------------------------------------------------------------------------
// 128-ch CSR gather on dinv-scaled bf16 table.
// ---------------------------------------------------------------------------
__global__ __launch_bounds__(256) void k_gatherb(
    const unsigned* __restrict__ hwb, const uint2* __restrict__ meta,
    const int* __restrict__ rowstart, const float* __restrict__ dinv,
    const float* __restrict__ bias, unsigned* __restrict__ aggb) {
  const int t = threadIdx.x;
  const int n = blockIdx.x * 4 + (t >> 6);
  if (n >= N_NODES) return;
  const unsigned lane = t & 63;
  const unsigned q = lane >> 4;   // edge slot 0..3
  const unsigned cl = lane & 15;  // uint4 group (8 ch) over 128 ch
  const int rs = rowstart[n], re = rowstart[n + 1];
  const uint4* hb4 = (const uint4*)hwb;
  float4 lo0 = make_float4(0.f, 0.f, 0.f, 0.f), hi0 = lo0;
  float4 lo1 = lo0, hi1 = lo0;
  int j = rs;
  for (; j + 8 <= re; j += 8) {
    uint2 m0 = meta[j + q], m1 = meta[j + 4 + q];
    union { unsigned u; float f; } w0, w1;
    w0.u = m0.x; w1.u = m1.x;
    uint4 v0 = hb4[(m0.y << 4) + cl];
    uint4 v1 = hb4[(m1.y << 4) + cl];
    fma4(lo0, w0.f, bf4(v0.x, v0.y));
    fma4(hi0, w0.f, bf4(v0.z, v0.w));
    fma4(lo1, w1.f, bf4(v1.x, v1.y));
    fma4(hi1, w1.f, bf4(v1.z, v1.w));
  }
  for (; j + 4 <= re; j += 4) {
    uint2 m0 = meta[j + q];
    union { unsigned u; float f; } w0;
    w0.u = m0.x;
    uint4 v0 = hb4[(m0.y << 4) + cl];
    fma4(lo0, w0.f, bf4(v0.x, v0.y));
    fma4(hi0, w0.f, bf4(v0.z, v0.w));
  }
  if (j + (int)q < re) {
    uint2 m0 = meta[j + q];
    union { unsigned u; float f; } w0;
    w0.u = m0.x;
    uint4 v0 = hb4[(m0.y << 4) + cl];
    fma4(lo1, w0.f, bf4(v0.x, v0.y));
    fma4(hi1, w0.f, bf4(v0.z, v0.w));
  }
  lo0.x += lo1.x; lo0.y += lo1.y; lo0.z += lo1.z; lo0.w += lo1.w;
  hi0.x += hi1.x; hi0.y += hi1.y; hi0.z += hi1.z; hi0.w += hi1.w;
#pragma unroll
  for (int m = 16; m <= 32; m <<= 1) {
    lo0.x += __shfl_xor(lo0.x, m);
    lo0.y += __shfl_xor(lo0.y, m);
    lo0.z += __shfl_xor(lo0.z, m);
    lo0.w += __shfl_xor(lo0.w, m);
    hi0.x += __shfl_xor(hi0.x, m);
    hi0.y += __shfl_xor(hi0.y, m);
    hi0.z += __shfl_xor(hi0.z, m);
    hi0.w += __shfl_xor(hi0.w, m);
  }
  if (q == 0) {
    float dv = dinv[n];
    uint4 sv = hb4[((unsigned)n << 4) + cl];
    float4 slo = bf4(sv.x, sv.y), shi = bf4(sv.z, sv.w);
    float4 blo = *(const float4*)&bias[cl * 8];
    float4 bhi = *(const float4*)&bias[cl * 8 + 4];
    uint4 o;
    o.x = packbf(dv * (lo0.x + slo.x) + blo.x, dv * (lo0.y + slo.y) + blo.y);
    o.y = packbf(dv * (lo0.z + slo.z) + blo.z, dv * (lo0.w + slo.w) + blo.w);
    o.z = packbf(dv * (hi0.x + shi.x) + bhi.x, dv * (hi0.y + shi.y) + bhi.y);
    o.w = packbf(dv * (hi0.z + shi.z) + bhi.z, dv * (hi0.w + shi.w) + bhi.w);
    ((uint4*)aggb)[((unsigned)n << 4) + cl] = o;
  }
}

// ---------------------------------------------------------------------------
// GraphNorm stats on bf16 table.
// ---------------------------------------------------------------------------
__global__ __launch_bounds__(512) void k_gstats(
    const unsigned* __restrict__ hb, const int* __restrict__ start,
    const float* __restrict__ gw, const float* __restrict__ gb,
    const float* __restrict__ gms, float* __restrict__ An,
    float* __restrict__ Bn) {
  int g = blockIdx.x;
  int s = start[g], e = start[g + 1];
  int t = threadIdx.x, p = t >> 7, c = t & 127;
  float sum = 0.f, sq = 0.f;
  for (int n = s + p; n < e; n += 4) {
    float v = bfat(hb + (size_t)n * 64, c);
    sum += v;
    sq += v * v;
  }
  __shared__ float S[4][128], Q[4][128];
  S[p][c] = sum;
  Q[p][c] = sq;
  __syncthreads();
  if (t < 128) {
    float cnt = (float)max(e - s, 1);
    float mean = (S[0][t] + S[1][t] + S[2][t] + S[3][t]) / cnt;
    float e2 = (Q[0][t] + Q[1][t] + Q[2][t] + Q[3][t]) / cnt;
    float ms = gms[t];
    float var = fmaxf(e2 - ms * (2.f - ms) * mean * mean, 0.f);
    float scale = gw[t] / sqrtf(var + EPS);
    An[(size_t)g * 128 + t] = scale;
    Bn[(size_t)g * 128 + t] = gb[t] - scale * ms * mean;
  }
}

// pooled[g,c] = mean over graph nodes of relu(A*h+B), h bf16
__global__ __launch_bounds__(512) void k_pool(
    const unsigned* __restrict__ hb, const int* __restrict__ start,
    const float* __restrict__ An, const float* __restrict__ Bn,
    float* __restrict__ pooled) {
  int g = blockIdx.x;
  int s = start[g], e = start[g + 1];
  int t = threadIdx.x, p = t >> 7, c = t & 127;
  float A = An[(size_t)g * 128 + c], B = Bn[(size_t)g * 128 + c];
  float sum = 0.f;
  for (int n = s + p; n < e; n += 4)
    sum += fmaxf(A * bfat(hb + (size_t)n * 64, c) + B, 0.f);
  __shared__ float S[4][128];
  S[p][c] = sum;
  __syncthreads();
  if (t < 128) {
    float cnt = (float)max(e - s, 1);
    pooled[g * 128 + t] = (S[0][t] + S[1][t] + S[2][t] + S[3][t]) / cnt;
  }
}

// MLP head: 128 ->256 (BN,ReLU) ->128 (BN,ReLU) ->1; writes out[g] and h2.
__global__ __launch_bounds__(256) void k_head(
    const float* __restrict__ pooled, const float* __restrict__ w0,
    const float* __restrict__ b0, const float* __restrict__ g0,
    const float* __restrict__ bb0, const float* __restrict__ w1,
    const float* __restrict__ b1, const float* __restrict__ g1,
    const float* __restrict__ bb1, const float* __restrict__ ow,
    const float* __restrict__ ob, float* __restrict__ out) {
  __shared__ float p[128], h1[256], h2[128];
  int g = blockIdx.x, t = threadIdx.x;
  const float inv = 1.0f / sqrtf(1.0f + EPS);
  if (t < 128) p[t] = pooled[g * 128 + t];
  __syncthreads();
  {
    float acc = b0[t];
#pragma unroll 8
    for (int k = 0; k < 128; ++k) acc += p[k] * w0[k * 256 + t];
    h1[t] = fmaxf(acc * inv * g0[t] + bb0[t], 0.f);
  }
  __syncthreads();
  if (t < 128) {
    float acc = b1[t];
#pragma unroll 8
    for (int k = 0; k < 256; ++k) acc += h1[k] * w1[k * 128 + t];
    float v = fmaxf(acc * inv * g1[t] + bb1[t], 0.f);
    h2[t] = v;
    out[N_GRAPHS + g * 128 + t] = v;
  }
  __syncthreads();
  if (t < 64) {
    float v = h2[t] * ow[t] + h2[t + 64] * ow[t + 64];
#pragma unroll
    for (int off = 32; off; off >>= 1) v += __shfl_down(v, off);
    if (t == 0) out[g] = v + ob[0];
  }
}

// ---------------------------------------------------------------------------
extern "C" void kernel_launch(void* const* d_in, const int* in_sizes, int n_in,
                              void* d_out, int out_size, void* d_ws,
                              size_t ws_size, hipStream_t stream) {
  const float* x = (const float*)d_in[0];
  const float* edge_attr = (const float*)d_in[1];
  const float* em_w1 = (const float*)d_in[2];
  const float* em_b1 = (const float*)d_in[3];
  const float* em_w2 = (const float*)d_in[4];
  const float* em_b2 = (const float*)d_in[5];
  const float* conv_w[3] = {(const float*)d_in[6], (const float*)d_in[8],
                            (const float*)d_in[10]};
  const float* conv_b[3] = {(const float*)d_in[7], (const float*)d_in[9],
                            (const float*)d_in[11]};
  const float* gn_w[3] = {(const float*)d_in[12], (const float*)d_in[15],
                          (const float*)d_in[18]};
  const float* gn_b[3] = {(const float*)d_in[13], (const float*)d_in[16],
                          (const float*)d_in[19]};
  const float* gn_ms[3] = {(const float*)d_in[14], (const float*)d_in[17],
                           (const float*)d_in[20]};
  const float* lin_w0 = (const float*)d_in[21];
  const float* lin_b0 = (const float*)d_in[22];
  const float* bn_g0 = (const float*)d_in[23];
  const float* bn_b0 = (const float*)d_in[24];
  const float* lin_w1 = (const float*)d_in[25];
  const float* lin_b1 = (const float*)d_in[26];
  const float* bn_g1 = (const float*)d_in[27];
  const float* bn_b1 = (const float*)d_in[28];
  const float* out_w = (const float*)d_in[29];
  const float* out_b = (const float*)d_in[30];
  const int* edge_index = (const int*)d_in[31];
  const int* batch = (const int*)d_in[32];
  const int* src = edge_index;
  const int* tgt = edge_index + N_EDGES;

  char* w = (char*)d_ws;
  size_t off = 0;
  auto carve = [&](size_t bytes) {
    void* p = w + off;
    off = (off + bytes + 511) & ~(size_t)511;
    return p;
  };
  float* dinv = (float*)carve((size_t)N_NODES * 4);
  int* rowstart = (int*)carve((size_t)(N_NODES + 1) * 4);
  int* bcnt = (int*)carve((size_t)NBUCK * 4);
  int* bbase = (int*)carve((size_t)(NBUCK + 1) * 4);
  int* gcur = (int*)carve((size_t)NBUCK * 4);
  uint2* mb = (uint2*)carve((size_t)N_EDGES * 8);
  uint2* meta = (uint2*)carve((size_t)N_EDGES * 8);
  int* start = (int*)carve((N_GRAPHS + 1) * 4);
  float* AB = (float*)carve((size_t)6 * N_GRAPHS * 128 * 4);
  unsigned* xb = (unsigned*)carve((size_t)N_NODES * 64 * 2);
  unsigned* aggxb = (unsigned*)carve((size_t)N_NODES * 64 * 2);
  unsigned* h1b = (unsigned*)carve((size_t)N_NODES * 128 * 2);
  unsigned* hwb = (unsigned*)carve((size_t)N_NODES * 128 * 2);
  unsigned* agg1b = (unsigned*)carve((size_t)N_NODES * 128 * 2);
  unsigned* agg2b = (unsigned*)carve((size_t)N_NODES * 128 * 2);
  unsigned short* wt0 = (unsigned short*)carve((size_t)128 * 64 * 2);
  unsigned short* wt1 = (unsigned short*)carve((size_t)128 * 128 * 2);
  unsigned short* wt2 = (unsigned short*)carve((size_t)128 * 128 * 2);
  float* pooled = (float*)carve((size_t)N_GRAPHS * 128 * 4);

  float* A0 = AB, *B0 = AB + N_GRAPHS * 128;
  float* A1 = AB + 2 * N_GRAPHS * 128, *B1 = AB + 3 * N_GRAPHS * 128;
  float* A2 = AB + 4 * N_GRAPHS * 128, *B2 = AB + 5 * N_GRAPHS * 128;

  hipMemsetAsync(bcnt, 0, (size_t)NBUCK * 4, stream);

  k_prep<<<PREP_BLOCKS, 256, 0, stream>>>(conv_w[1], conv_w[2], wt1, wt2,
                                          conv_w[0], wt0, batch, start, tgt,
                                          bcnt);
  k_bscan<<<1, 1024, 0, stream>>>(bcnt, bbase, gcur);
  k_scatter<<<(N_EDGES + 255) / 256, 256, 0, stream>>>(
      edge_attr, em_w1, em_b1, em_w2, em_b2, src, tgt, gcur, mb);
  k_csr<<<NUSED, 256, 0, stream>>>(mb, bbase, meta, rowstart, dinv);
  k_cvt<<<(N_NODES * 8 + 255) / 256, 256, 0, stream>>>(x, dinv, xb);

  const int ggrid = (N_NODES + 3) / 4;
  const int hwgrid = (N_NODES + 63) / 64;

  // layer 0: aggregate-first (bf16, dinv folded), MFMA GEMM + bias -> h1b.
  k_gather64b<<<ggrid, 256, 0, stream>>>(xb, meta, rowstart, dinv, aggxb);
  k_hw_mfma0<<<hwgrid, 256, 0, stream>>>((unsigned short*)aggxb, wt0,
                                         conv_b[0], (unsigned short*)h1b);
  k_gstats<<<N_GRAPHS, 512, 0, stream>>>(h1b, start, gn_w[0], gn_b[0],
                                         gn_ms[0], A0, B0);
  // layer 1
  k_hw_mfma<<<hwgrid, 256, 0, stream>>>(h1b, wt1, batch, A0, B0, dinv,
                                        (unsigned short*)hwb);
  k_gatherb<<<ggrid, 256, 0, stream>>>(hwb, meta, rowstart, dinv, conv_b[1],
                                       agg1b);
  k_gstats<<<N_GRAPHS, 512, 0, stream>>>(agg1b, start, gn_w[1], gn_b[1],
                                         gn_ms[1], A1, B1);
  // layer 2
  k_hw_mfma<<<hwgrid, 256, 0, stream>>>(agg1b, wt2, batch, A1, B1, dinv,
                                        (unsigned short*)hwb);
  k_gatherb<<<ggrid, 256, 0, stream>>>(hwb, meta, rowstart, dinv, conv_b[2],
                                       agg2b);
  k_gstats<<<N_GRAPHS, 512, 0, stream>>>(agg2b, start, gn_w[2], gn_b[2],
                                         gn_ms[2], A2, B2);

  k_pool<<<N_GRAPHS, 512, 0, stream>>>(agg2b, start, A2, B2, pooled);
  k_head<<<N_GRAPHS, 256, 0, stream>>>(pooled, lin_w0, lin_b0, bn_g0, bn_b0,
                                       lin_w1, lin_b1, bn_g1, bn_b1, out_w,
                                       out_b, (float*)d_out);
}

// Round 14
// 500.849 us; speedup vs baseline: 1.6221x; 1.6221x over previous
//
#include <hip/hip_runtime.h>

#define N_NODES 100000
#define N_EDGES 1600000
#define N_GRAPHS 256
#define EPS 1e-5f

#define NBUCK 1024            // buckets = tgt >> 7 (782 used)
#define NUSED 782
#define NBLK 256              // scatter blocks
#define EPB (N_EDGES / NBLK)  // 6250 edges per scatter block

// k_prep block ranges
#define WB 128   // W1/W2 transpose
#define W0B 32   // W0 transpose
#define SB 2     // graph starts
#define PREP_BLOCKS (WB + W0B + SB + NBLK)

typedef __attribute__((ext_vector_type(8))) short bfrag8;  // 8 bf16
typedef __attribute__((ext_vector_type(4))) float facc4;   // 4 f32 acc

__device__ __forceinline__ void fma4(float4& a, float s, const float4& w) {
  a.x += s * w.x; a.y += s * w.y; a.z += s * w.z; a.w += s * w.w;
}

__device__ __forceinline__ unsigned short f2bf(float f) {
  union { float f; unsigned u; } x;
  x.f = f;
  unsigned r = x.u + 0x7FFF + ((x.u >> 16) & 1);  // RNE
  return (unsigned short)(r >> 16);
}
__device__ __forceinline__ unsigned packbf(float a, float b) {
  return (unsigned)f2bf(a) | ((unsigned)f2bf(b) << 16);
}
__device__ __forceinline__ float4 bf4(unsigned lo, unsigned hi) {
  union { unsigned u; float f; } a, b, c, d;
  a.u = lo << 16;
  b.u = lo & 0xFFFF0000u;
  c.u = hi << 16;
  d.u = hi & 0xFFFF0000u;
  return make_float4(a.f, b.f, c.f, d.f);
}
__device__ __forceinline__ float bfat(const unsigned* tb, int idx) {
  unsigned u = tb[idx >> 1];
  union { unsigned u; float f; } v;
  v.u = (idx & 1) ? (u & 0xFFFF0000u) : (u << 16);
  return v.f;
}

// ---------------------------------------------------------------------------
// Prep: W transposes, graph starts, per-scatter-block bucket histogram.
// ---------------------------------------------------------------------------
__global__ __launch_bounds__(256) void k_prep(
    const float* __restrict__ cw1, const float* __restrict__ cw2,
    unsigned short* __restrict__ wt1, unsigned short* __restrict__ wt2,
    const float* __restrict__ cw0, unsigned short* __restrict__ wt0,
    const int* __restrict__ batch, int* __restrict__ start,
    const int* __restrict__ tgt, int* __restrict__ hists) {
  __shared__ int h[NBUCK];
  const int b = blockIdx.x;
  const int t = threadIdx.x;
  if (b < WB) {
    int half = b >> 6;              // 0: w1, 1: w2
    int id = (b & 63) * 256 + t;    // 0..16383
    const float* w = half ? cw2 : cw1;
    unsigned short* o = half ? wt2 : wt1;
    int n = id >> 7, k = id & 127;
    o[n * 128 + k] = f2bf(w[k * 128 + n]);
  } else if (b < WB + W0B) {
    int id = (b - WB) * 256 + t;
    if (id >= 8192) return;
    int n = id >> 6, k = id & 63;
    wt0[n * 64 + k] = f2bf(cw0[k * 128 + n]);
  } else if (b < WB + W0B + SB) {
    int g = (b - WB - W0B) * 256 + t;
    if (g > N_GRAPHS) return;
    int lo = 0, hi = N_NODES;
    while (lo < hi) {
      int mid = (lo + hi) >> 1;
      if (batch[mid] < g) lo = mid + 1; else hi = mid;
    }
    start[g] = lo;
  } else {
    const int blk = b - WB - W0B - SB;  // 0..NBLK-1
    for (int i = t; i < NBUCK; i += 256) h[i] = 0;
    __syncthreads();
    const int s = blk * EPB, e = s + EPB;
    for (int j = s + t; j < e; j += 256) atomicAdd(&h[tgt[j] >> 7], 1);
    __syncthreads();
    for (int i = t; i < NBUCK; i += 256) hists[blk * NBUCK + i] = h[i];
  }
}

// ---------------------------------------------------------------------------
// Bucket scan: 1 block x 1024. tot[b] -> exclusive bbase; per-(block,bucket)
// cursor bases.
// ---------------------------------------------------------------------------
__global__ __launch_bounds__(1024) void k_bscan(const int* __restrict__ hists,
                                                int* __restrict__ bbase,
                                                int* __restrict__ cursor) {
  __shared__ int s[NBUCK];
  const int b = threadIdx.x;
  int tot = 0;
  for (int k = 0; k < NBLK; ++k) tot += hists[k * NBUCK + b];
  s[b] = tot;
  __syncthreads();
  for (int off = 1; off < NBUCK; off <<= 1) {
    int u = (b >= off) ? s[b - off] : 0;
    __syncthreads();
    s[b] += u;
    __syncthreads();
  }
  int base = s[b] - tot;  // exclusive
  bbase[b] = base;
  if (b == NBUCK - 1) bbase[NBUCK] = N_EDGES;
  int c = base;
  for (int k = 0; k < NBLK; ++k) {
    cursor[k * NBUCK + b] = c;
    c += hists[k * NBUCK + b];
  }
}

// ---------------------------------------------------------------------------
// Fused edge-MLP + bucket scatter (LDS cursors, contiguous destinations):
// mb[pos] = {bits(ew), src | (tgt&127)<<25}.
// ---------------------------------------------------------------------------
__global__ __launch_bounds__(256) void k_scatter(
    const float* __restrict__ ea, const float* __restrict__ w1,
    const float* __restrict__ b1, const float* __restrict__ w2,
    const float* __restrict__ b2, const int* __restrict__ src,
    const int* __restrict__ tgt, const int* __restrict__ cursor,
    uint2* __restrict__ mb) {
  __shared__ float W1[128], B1[16], W2[16];
  __shared__ int cur[NBUCK];
  const int blk = blockIdx.x, t = threadIdx.x;
  if (t < 128) W1[t] = w1[t];
  if (t < 16) { B1[t] = b1[t]; W2[t] = w2[t]; }
  for (int i = t; i < NBUCK; i += 256) cur[i] = cursor[blk * NBUCK + i];
  __syncthreads();
  const int s = blk * EPB, e = s + EPB;
  for (int j = s + t; j < e; j += 256) {
    const float4* ap = (const float4*)(ea + (size_t)j * 8);
    float4 a0 = ap[0], a1 = ap[1];
    float a[8] = {a0.x, a0.y, a0.z, a0.w, a1.x, a1.y, a1.z, a1.w};
    float out = b2[0];
#pragma unroll
    for (int i = 0; i < 16; ++i) {
      float h = B1[i];
#pragma unroll
      for (int jj = 0; jj < 8; ++jj) h += a[jj] * W1[i * 8 + jj];
      out += fmaxf(h, 0.f) * W2[i];
    }
    int d = tgt[j];
    int bin = d >> 7;
    int pos = atomicAdd(&cur[bin], 1);
    union { float f; unsigned u; } w;
    w.f = out;
    mb[pos] = make_uint2(w.u, (unsigned)src[j] | ((unsigned)(d & 127) << 25));
  }
}

// ---------------------------------------------------------------------------
// Bucket -> CSR + dinv: one block per bucket. Pass 1 bins counts AND float
// deg sums (LDS atomics); scan -> rowstart + dinv; pass 2 places meta.
// ---------------------------------------------------------------------------
__global__ __launch_bounds__(256) void k_csr(const uint2* __restrict__ mb,
                                             const int* __restrict__ bbase,
                                             uint2* __restrict__ meta,
                                             int* __restrict__ rowstart,
                                             float* __restrict__ dinv) {
  __shared__ int hist[128];
  __shared__ float degf[128];
  __shared__ int cur[128];
  const int b = blockIdx.x;
  const int t = threadIdx.x;
  const int s = bbase[b], e = bbase[b + 1];
  if (t < 128) { hist[t] = 0; degf[t] = 0.f; }
  __syncthreads();
  for (int j = s + t; j < e; j += 256) {
    uint2 m = mb[j];
    int bin = m.y >> 25;
    atomicAdd(&hist[bin], 1);
    union { unsigned u; float f; } w;
    w.u = m.x;
    atomicAdd(&degf[bin], w.f);
  }
  __syncthreads();
  int own = (t < 128) ? hist[t] : 0;
  for (int off = 1; off < 128; off <<= 1) {
    int u = (t >= off && t < 128) ? hist[t - off] : 0;
    __syncthreads();
    if (t < 128) hist[t] += u;
    __syncthreads();
  }
  if (t < 128) {
    int excl = hist[t] - own;
    int node = b * 128 + t;
    if (node <= N_NODES) rowstart[node] = s + excl;
    if (node < N_NODES) {
      float d = 1.f + degf[t];
      dinv[node] = d > 0.f ? rsqrtf(d) : 0.f;
    }
    cur[t] = s + excl;
  }
  __syncthreads();
  for (int j = s + t; j < e; j += 256) {
    uint2 m = mb[j];
    int bin = m.y >> 25;
    int pos = atomicAdd(&cur[bin], 1);
    meta[pos] = make_uint2(m.x, m.y & 0x1FFFFFFu);
  }
}

// x (f32) -> xb = bf16(dinv*x), 8 ch/thread
__global__ __launch_bounds__(256) void k_cvt(const float* __restrict__ x,
                                             const float* __restrict__ dinv,
                                             unsigned* __restrict__ xb) {
  int i = blockIdx.x * 256 + threadIdx.x;
  if (i >= N_NODES * 8) return;
  int n = i >> 3;
  float dv = dinv[n];
  const float4* p = (const float4*)(x + (size_t)i * 8);
  float4 a = p[0], b = p[1];
  uint4 o;
  o.x = packbf(dv * a.x, dv * a.y);
  o.y = packbf(dv * a.z, dv * a.w);
  o.z = packbf(dv * b.x, dv * b.y);
  o.w = packbf(dv * b.z, dv * b.w);
  ((uint4*)xb)[i] = o;
}

// ---------------------------------------------------------------------------
// 64-ch CSR gather on pre-scaled bf16 x' (= dinv*x).
// ---------------------------------------------------------------------------
__global__ __launch_bounds__(256) void k_gather64b(
    const unsigned* __restrict__ xb, const uint2* __restrict__ meta,
    const int* __restrict__ rowstart, const float* __restrict__ dinv,
    unsigned* __restrict__ aggxb) {
  const int t = threadIdx.x;
  const int n = blockIdx.x * 4 + (t >> 6);
  if (n >= N_NODES) return;
  const unsigned lane = t & 63;
  const unsigned q = lane >> 3;   // edge slot 0..7
  const unsigned cl = lane & 7;   // uint4 group (8 ch) over 64 ch
  const int rs = rowstart[n], re = rowstart[n + 1];
  const uint4* x4 = (const uint4*)xb;
  float4 lo0 = make_float4(0.f, 0.f, 0.f, 0.f), hi0 = lo0;
  float4 lo1 = lo0, hi1 = lo0;
  int j = rs;
  for (; j + 16 <= re; j += 16) {
    uint2 m0 = meta[j + q], m1 = meta[j + 8 + q];
    union { unsigned u; float f; } w0, w1;
    w0.u = m0.x; w1.u = m1.x;
    uint4 v0 = x4[(m0.y << 3) + cl];
    uint4 v1 = x4[(m1.y << 3) + cl];
    fma4(lo0, w0.f, bf4(v0.x, v0.y));
    fma4(hi0, w0.f, bf4(v0.z, v0.w));
    fma4(lo1, w1.f, bf4(v1.x, v1.y));
    fma4(hi1, w1.f, bf4(v1.z, v1.w));
  }
  for (; j + 8 <= re; j += 8) {
    uint2 m0 = meta[j + q];
    union { unsigned u; float f; } w0;
    w0.u = m0.x;
    uint4 v0 = x4[(m0.y << 3) + cl];
    fma4(lo0, w0.f, bf4(v0.x, v0.y));
    fma4(hi0, w0.f, bf4(v0.z, v0.w));
  }
  if (j + (int)q < re) {
    uint2 m0 = meta[j + q];
    union { unsigned u; float f; } w0;
    w0.u = m0.x;
    uint4 v0 = x4[(m0.y << 3) + cl];
    fma4(lo1, w0.f, bf4(v0.x, v0.y));
    fma4(hi1, w0.f, bf4(v0.z, v0.w));
  }
  lo0.x += lo1.x; lo0.y += lo1.y; lo0.z += lo1.z; lo0.w += lo1.w;
  hi0.x += hi1.x; hi0.y += hi1.y; hi0.z += hi1.z; hi0.w += hi1.w;
#pragma unroll
  for (int m = 8; m <= 32; m <<= 1) {
    lo0.x += __shfl_xor(lo0.x, m);
    lo0.y += __shfl_xor(lo0.y, m);
    lo0.z += __shfl_xor(lo0.z, m);
    lo0.w += __shfl_xor(lo0.w, m);
    hi0.x += __shfl_xor(hi0.x, m);
    hi0.y += __shfl_xor(hi0.y, m);
    hi0.z += __shfl_xor(hi0.z, m);
    hi0.w += __shfl_xor(hi0.w, m);
  }
  if (q == 0) {
    float dv = dinv[n];
    uint4 sv = x4[((unsigned)n << 3) + cl];
    float4 slo = bf4(sv.x, sv.y), shi = bf4(sv.z, sv.w);
    uint4 o;
    o.x = packbf(dv * (lo0.x + slo.x), dv * (lo0.y + slo.y));
    o.y = packbf(dv * (lo0.z + slo.z), dv * (lo0.w + slo.w));
    o.z = packbf(dv * (hi0.x + shi.x), dv * (hi0.y + shi.y));
    o.w = packbf(dv * (hi0.z + shi.z), dv * (hi0.w + shi.w));
    ((uint4*)aggxb)[((unsigned)n << 3) + cl] = o;
  }
}

// ---------------------------------------------------------------------------
// Layer-0 MFMA GEMM: h1b = bf16( aggxb @ W0 + b0 ).  CIN=64.
// ---------------------------------------------------------------------------
__global__ __launch_bounds__(256) void k_hw_mfma0(
    const unsigned short* __restrict__ aggxb,
    const unsigned short* __restrict__ wt0, const float* __restrict__ bias,
    unsigned short* __restrict__ h1b) {
  __shared__ unsigned short Asb[64][72];
  __shared__ unsigned short Wsb[128][72];
  const int t = threadIdx.x;
  const int base = blockIdx.x * 64;

  for (int i = t; i < 1024; i += 256) {
    int nr = i >> 3, k8 = (i & 7) * 8;
    *(uint4*)&Wsb[nr][k8] = *(const uint4*)&wt0[nr * 64 + k8];
  }
  {
    const int ln = t >> 2;
    const int kp = (t & 3) * 16;
    const int n = base + ln;
    if (n < N_NODES) {
      *(uint4*)&Asb[ln][kp] = *(const uint4*)&aggxb[(size_t)n * 64 + kp];
      *(uint4*)&Asb[ln][kp + 8] = *(const uint4*)&aggxb[(size_t)n * 64 + kp + 8];
    } else {
      uint4 z = make_uint4(0, 0, 0, 0);
      *(uint4*)&Asb[ln][kp] = z;
      *(uint4*)&Asb[ln][kp + 8] = z;
    }
  }
  __syncthreads();

  const int wv = t >> 6;
  const int lr = t & 15;
  const int lk = (t >> 4) & 3;
  const int m0 = wv * 16;

  bfrag8 af[2];
#pragma unroll
  for (int kc = 0; kc < 2; ++kc)
    af[kc] = *(const bfrag8*)&Asb[m0 + lr][kc * 32 + lk * 8];

#pragma unroll
  for (int nt = 0; nt < 8; ++nt) {
    facc4 c = {0.f, 0.f, 0.f, 0.f};
#pragma unroll
    for (int kc = 0; kc < 2; ++kc) {
      bfrag8 bf = *(const bfrag8*)&Wsb[nt * 16 + lr][kc * 32 + lk * 8];
      c = __builtin_amdgcn_mfma_f32_16x16x32_bf16(af[kc], bf, c, 0, 0, 0);
    }
    int col = nt * 16 + lr;
    float bv = bias[col];
#pragma unroll
    for (int r = 0; r < 4; ++r) {
      int n = base + m0 + lk * 4 + r;
      if (n < N_NODES) h1b[(size_t)n * 128 + col] = f2bf(c[r] + bv);
    }
  }
}

// ---------------------------------------------------------------------------
// Layers 1-2 MFMA GEMM: hwb = bf16( dinv[n] * (relu(A*h+B) @ W) ).
// ---------------------------------------------------------------------------
__global__ __launch_bounds__(256) void k_hw_mfma(
    const unsigned* __restrict__ hb, const unsigned short* __restrict__ wt,
    const int* __restrict__ batch, const float* __restrict__ An,
    const float* __restrict__ Bn, const float* __restrict__ dinv,
    unsigned short* __restrict__ hwb) {
  __shared__ unsigned short Asb[64][136];
  __shared__ unsigned short Wsb[128][136];
  const int t = threadIdx.x;
  const int base = blockIdx.x * 64;

  for (int i = t; i < 2048; i += 256) {
    int nr = i >> 4, k8 = (i & 15) * 8;
    *(uint4*)&Wsb[nr][k8] = *(const uint4*)&wt[nr * 128 + k8];
  }
  {
    const int ln = t >> 2;
    const int cg = (t & 3) * 32;
    const int n = base + ln;
    if (n < N_NODES) {
      const int g = batch[n];
      const uint4* hp = (const uint4*)(hb + (size_t)n * 64);
      const float* Ap = An + (size_t)g * 128;
      const float* Bp = Bn + (size_t)g * 128;
#pragma unroll
      for (int qq = 0; qq < 4; ++qq) {
        int c = cg + qq * 8;
        uint4 v = hp[(t & 3) * 4 + qq];
        float4 lo = bf4(v.x, v.y);
        float4 hi = bf4(v.z, v.w);
        float4 Alo = *(const float4*)&Ap[c], Blo = *(const float4*)&Bp[c];
        float4 Ahi = *(const float4*)&Ap[c + 4], Bhi = *(const float4*)&Bp[c + 4];
        uint4 o;
        o.x = packbf(fmaxf(Alo.x * lo.x + Blo.x, 0.f),
                     fmaxf(Alo.y * lo.y + Blo.y, 0.f));
        o.y = packbf(fmaxf(Alo.z * lo.z + Blo.z, 0.f),
                     fmaxf(Alo.w * lo.w + Blo.w, 0.f));
        o.z = packbf(fmaxf(Ahi.x * hi.x + Bhi.x, 0.f),
                     fmaxf(Ahi.y * hi.y + Bhi.y, 0.f));
        o.w = packbf(fmaxf(Ahi.z * hi.z + Bhi.z, 0.f),
                     fmaxf(Ahi.w * hi.w + Bhi.w, 0.f));
        *(uint4*)&Asb[ln][c] = o;
      }
    } else {
      uint4 z = make_uint4(0, 0, 0, 0);
#pragma unroll
      for (int qq = 0; qq < 4; ++qq) *(uint4*)&Asb[ln][cg + qq * 8] = z;
    }
  }
  __syncthreads();

  const int wv = t >> 6;
  const int lr = t & 15;
  const int lk = (t >> 4) & 3;
  const int m0 = wv * 16;

  bfrag8 af[4];
#pragma unroll
  for (int kc = 0; kc < 4; ++kc)
    af[kc] = *(const bfrag8*)&Asb[m0 + lr][kc * 32 + lk * 8];

  float dv[4];
#pragma unroll
  for (int r = 0; r < 4; ++r) {
    int n = base + m0 + lk * 4 + r;
    dv[r] = (n < N_NODES) ? dinv[n] : 0.f;
  }

#pragma unroll
  for (int nt = 0; nt < 8; ++nt) {
    facc4 c = {0.f, 0.f, 0.f, 0.f};
#pragma unroll
    for (int kc = 0; kc < 4; ++kc) {
      bfrag8 bf = *(const bfrag8*)&Wsb[nt * 16 + lr][kc * 32 + lk * 8];
      c = __builtin_amdgcn_mfma_f32_16x16x32_bf16(af[kc], bf, c, 0, 0, 0);
    }
    int col = nt * 16 + lr;
#pragma unroll
    for (int r = 0; r < 4; ++r) {
      int n = base + m0 + lk * 4 + r;
      if (n < N_NODES) hwb[(size_t)n * 128 + col] = f2bf(dv[r] * c[r]);
    }
  }
}

// ---------------------------------------------------------------------------
// 128-ch CSR gather on dinv-scaled bf16 table.
// ---------------------------------------------------------------------------
__global__ __launch_bounds__(256) void k_gatherb(
    const unsigned* __restrict__ hwb, const uint2* __restrict__ meta,
    const int* __restrict__ rowstart, const float* __restrict__ dinv,
    const float* __restrict__ bias, unsigned* __restrict__ aggb) {
  const int t = threadIdx.x;
  const int n = blockIdx.x * 4 + (t >> 6);
  if (n >= N_NODES) return;
  const unsigned lane = t & 63;
  const unsigned q = lane >> 4;   // edge slot 0..3
  const unsigned cl = lane & 15;  // uint4 group (8 ch) over 128 ch
  const int rs = rowstart[n], re = rowstart[n + 1];
  const uint4* hb4 = (const uint4*)hwb;
  float4 lo0 = make_float4(0.f, 0.f, 0.f, 0.f), hi0 = lo0;
  float4 lo1 = lo0, hi1 = lo0;
  int j = rs;
  for (; j + 8 <= re; j += 8) {
    uint2 m0 = meta[j + q], m1 = meta[j + 4 + q];
    union { unsigned u; float f; } w0, w1;
    w0.u = m0.x; w1.u = m1.x;
    uint4 v0 = hb4[(m0.y << 4) + cl];
    uint4 v1 = hb4[(m1.y << 4) + cl];
    fma4(lo0, w0.f, bf4(v0.x, v0.y));
    fma4(hi0, w0.f, bf4(v0.z, v0.w));
    fma4(lo1, w1.f, bf4(v1.x, v1.y));
    fma4(hi1, w1.f, bf4(v1.z, v1.w));
  }
  for (; j + 4 <= re; j += 4) {
    uint2 m0 = meta[j + q];
    union { unsigned u; float f; } w0;
    w0.u = m0.x;
    uint4 v0 = hb4[(m0.y << 4) + cl];
    fma4(lo0, w0.f, bf4(v0.x, v0.y));
    fma4(hi0, w0.f, bf4(v0.z, v0.w));
  }
  if (j + (int)q < re) {
    uint2 m0 = meta[j + q];
    union { unsigned u; float f; } w0;
    w0.u = m0.x;
    uint4 v0 = hb4[(m0.y << 4) + cl];
    fma4(lo1, w0.f, bf4(v0.x, v0.y));
    fma4(hi1, w0.f, bf4(v0.z, v0.w));
  }
  lo0.x += lo1.x; lo0.y += lo1.y; lo0.z += lo1.z; lo0.w += lo1.w;
  hi0.x += hi1.x; hi0.y += hi1.y; hi0.z += hi1.z; hi0.w += hi1.w;
#pragma unroll
  for (int m = 16; m <= 32; m <<= 1) {
    lo0.x += __shfl_xor(lo0.x, m);
    lo0.y += __shfl_xor(lo0.y, m);
    lo0.z += __shfl_xor(lo0.z, m);
    lo0.w += __shfl_xor(lo0.w, m);
    hi0.x += __shfl_xor(hi0.x, m);
    hi0.y += __shfl_xor(hi0.y, m);
    hi0.z += __shfl_xor(hi0.z, m);
    hi0.w += __shfl_xor(hi0.w, m);
  }
  if (q == 0) {
    float dv = dinv[n];
    uint4 sv = hb4[((unsigned)n << 4) + cl];
    float4 slo = bf4(sv.x, sv.y), shi = bf4(sv.z, sv.w);
    float4 blo = *(const float4*)&bias[cl * 8];
    float4 bhi = *(const float4*)&bias[cl * 8 + 4];
    uint4 o;
    o.x = packbf(dv * (lo0.x + slo.x) + blo.x, dv * (lo0.y + slo.y) + blo.y);
    o.y = packbf(dv * (lo0.z + slo.z) + blo.z, dv * (lo0.w + slo.w) + blo.w);
    o.z = packbf(dv * (hi0.x + shi.x) + bhi.x, dv * (hi0.y + shi.y) + bhi.y);
    o.w = packbf(dv * (hi0.z + shi.z) + bhi.z, dv * (hi0.w + shi.w) + bhi.w);
    ((uint4*)aggb)[((unsigned)n << 4) + cl] = o;
  }
}

// ---------------------------------------------------------------------------
// GraphNorm stats on bf16 table.
// ---------------------------------------------------------------------------
__global__ __launch_bounds__(512) void k_gstats(
    const unsigned* __restrict__ hb, const int* __restrict__ start,
    const float* __restrict__ gw, const float* __restrict__ gb,
    const float* __restrict__ gms, float* __restrict__ An,
    float* __restrict__ Bn) {
  int g = blockIdx.x;
  int s = start[g], e = start[g + 1];
  int t = threadIdx.x, p = t >> 7, c = t & 127;
  float sum = 0.f, sq = 0.f;
  for (int n = s + p; n < e; n += 4) {
    float v = bfat(hb + (size_t)n * 64, c);
    sum += v;
    sq += v * v;
  }
  __shared__ float S[4][128], Q[4][128];
  S[p][c] = sum;
  Q[p][c] = sq;
  __syncthreads();
  if (t < 128) {
    float cnt = (float)max(e - s, 1);
    float mean = (S[0][t] + S[1][t] + S[2][t] + S[3][t]) / cnt;
    float e2 = (Q[0][t] + Q[1][t] + Q[2][t] + Q[3][t]) / cnt;
    float ms = gms[t];
    float var = fmaxf(e2 - ms * (2.f - ms) * mean * mean, 0.f);
    float scale = gw[t] / sqrtf(var + EPS);
    An[(size_t)g * 128 + t] = scale;
    Bn[(size_t)g * 128 + t] = gb[t] - scale * ms * mean;
  }
}

// pooled[g,c] = mean over graph nodes of relu(A*h+B), h bf16
__global__ __launch_bounds__(512) void k_pool(
    const unsigned* __restrict__ hb, const int* __restrict__ start,
    const float* __restrict__ An, const float* __restrict__ Bn,
    float* __restrict__ pooled) {
  int g = blockIdx.x;
  int s = start[g], e = start[g + 1];
  int t = threadIdx.x, p = t >> 7, c = t & 127;
  float A = An[(size_t)g * 128 + c], B = Bn[(size_t)g * 128 + c];
  float sum = 0.f;
  for (int n = s + p; n < e; n += 4)
    sum += fmaxf(A * bfat(hb + (size_t)n * 64, c) + B, 0.f);
  __shared__ float S[4][128];
  S[p][c] = sum;
  __syncthreads();
  if (t < 128) {
    float cnt = (float)max(e - s, 1);
    pooled[g * 128 + t] = (S[0][t] + S[1][t] + S[2][t] + S[3][t]) / cnt;
  }
}

// MLP head: 128 ->256 (BN,ReLU) ->128 (BN,ReLU) ->1; writes out[g] and h2.
__global__ __launch_bounds__(256) void k_head(
    const float* __restrict__ pooled, const float* __restrict__ w0,
    const float* __restrict__ b0, const float* __restrict__ g0,
    const float* __restrict__ bb0, const float* __restrict__ w1,
    const float* __restrict__ b1, const float* __restrict__ g1,
    const float* __restrict__ bb1, const float* __restrict__ ow,
    const float* __restrict__ ob, float* __restrict__ out) {
  __shared__ float p[128], h1[256], h2[128];
  int g = blockIdx.x, t = threadIdx.x;
  const float inv = 1.0f / sqrtf(1.0f + EPS);
  if (t < 128) p[t] = pooled[g * 128 + t];
  __syncthreads();
  {
    float acc = b0[t];
#pragma unroll 8
    for (int k = 0; k < 128; ++k) acc += p[k] * w0[k * 256 + t];
    h1[t] = fmaxf(acc * inv * g0[t] + bb0[t], 0.f);
  }
  __syncthreads();
  if (t < 128) {
    float acc = b1[t];
#pragma unroll 8
    for (int k = 0; k < 256; ++k) acc += h1[k] * w1[k * 128 + t];
    float v = fmaxf(acc * inv * g1[t] + bb1[t], 0.f);
    h2[t] = v;
    out[N_GRAPHS + g * 128 + t] = v;
  }
  __syncthreads();
  if (t < 64) {
    float v = h2[t] * ow[t] + h2[t + 64] * ow[t + 64];
#pragma unroll
    for (int off = 32; off; off >>= 1) v += __shfl_down(v, off);
    if (t == 0) out[g] = v + ob[0];
  }
}

// ---------------------------------------------------------------------------
extern "C" void kernel_launch(void* const* d_in, const int* in_sizes, int n_in,
                              void* d_out, int out_size, void* d_ws,
                              size_t ws_size, hipStream_t stream) {
  const float* x = (const float*)d_in[0];
  const float* edge_attr = (const float*)d_in[1];
  const float* em_w1 = (const float*)d_in[2];
  const float* em_b1 = (const float*)d_in[3];
  const float* em_w2 = (const float*)d_in[4];
  const float* em_b2 = (const float*)d_in[5];
  const float* conv_w[3] = {(const float*)d_in[6], (const float*)d_in[8],
                            (const float*)d_in[10]};
  const float* conv_b[3] = {(const float*)d_in[7], (const float*)d_in[9],
                            (const float*)d_in[11]};
  const float* gn_w[3] = {(const float*)d_in[12], (const float*)d_in[15],
                          (const float*)d_in[18]};
  const float* gn_b[3] = {(const float*)d_in[13], (const float*)d_in[16],
                          (const float*)d_in[19]};
  const float* gn_ms[3] = {(const float*)d_in[14], (const float*)d_in[17],
                           (const float*)d_in[20]};
  const float* lin_w0 = (const float*)d_in[21];
  const float* lin_b0 = (const float*)d_in[22];
  const float* bn_g0 = (const float*)d_in[23];
  const float* bn_b0 = (const float*)d_in[24];
  const float* lin_w1 = (const float*)d_in[25];
  const float* lin_b1 = (const float*)d_in[26];
  const float* bn_g1 = (const float*)d_in[27];
  const float* bn_b1 = (const float*)d_in[28];
  const float* out_w = (const float*)d_in[29];
  const float* out_b = (const float*)d_in[30];
  const int* edge_index = (const int*)d_in[31];
  const int* batch = (const int*)d_in[32];
  const int* src = edge_index;
  const int* tgt = edge_index + N_EDGES;

  char* w = (char*)d_ws;
  size_t off = 0;
  auto carve = [&](size_t bytes) {
    void* p = w + off;
    off = (off + bytes + 511) & ~(size_t)511;
    return p;
  };
  float* dinv = (float*)carve((size_t)N_NODES * 4);
  int* rowstart = (int*)carve((size_t)(N_NODES + 1) * 4);
  int* hists = (int*)carve((size_t)NBLK * NBUCK * 4);
  int* cursor = (int*)carve((size_t)NBLK * NBUCK * 4);
  int* bbase = (int*)carve((size_t)(NBUCK + 1) * 4);
  uint2* mb = (uint2*)carve((size_t)N_EDGES * 8);
  uint2* meta = (uint2*)carve((size_t)N_EDGES * 8);
  int* start = (int*)carve((N_GRAPHS + 1) * 4);
  float* AB = (float*)carve((size_t)6 * N_GRAPHS * 128 * 4);
  unsigned* xb = (unsigned*)carve((size_t)N_NODES * 64 * 2);
  unsigned* aggxb = (unsigned*)carve((size_t)N_NODES * 64 * 2);
  unsigned* h1b = (unsigned*)carve((size_t)N_NODES * 128 * 2);
  unsigned* hwb = (unsigned*)carve((size_t)N_NODES * 128 * 2);
  unsigned* agg1b = (unsigned*)carve((size_t)N_NODES * 128 * 2);
  unsigned* agg2b = (unsigned*)carve((size_t)N_NODES * 128 * 2);
  unsigned short* wt0 = (unsigned short*)carve((size_t)128 * 64 * 2);
  unsigned short* wt1 = (unsigned short*)carve((size_t)128 * 128 * 2);
  unsigned short* wt2 = (unsigned short*)carve((size_t)128 * 128 * 2);
  float* pooled = (float*)carve((size_t)N_GRAPHS * 128 * 4);

  float* A0 = AB, *B0 = AB + N_GRAPHS * 128;
  float* A1 = AB + 2 * N_GRAPHS * 128, *B1 = AB + 3 * N_GRAPHS * 128;
  float* A2 = AB + 4 * N_GRAPHS * 128, *B2 = AB + 5 * N_GRAPHS * 128;

  k_prep<<<PREP_BLOCKS, 256, 0, stream>>>(conv_w[1], conv_w[2], wt1, wt2,
                                          conv_w[0], wt0, batch, start, tgt,
                                          hists);
  k_bscan<<<1, 1024, 0, stream>>>(hists, bbase, cursor);
  k_scatter<<<NBLK, 256, 0, stream>>>(edge_attr, em_w1, em_b1, em_w2, em_b2,
                                      src, tgt, cursor, mb);
  k_csr<<<NUSED, 256, 0, stream>>>(mb, bbase, meta, rowstart, dinv);
  k_cvt<<<(N_NODES * 8 + 255) / 256, 256, 0, stream>>>(x, dinv, xb);

  const int ggrid = (N_NODES + 3) / 4;
  const int hwgrid = (N_NODES + 63) / 64;

  // layer 0: aggregate-first (bf16, dinv folded), MFMA GEMM + bias -> h1b.
  k_gather64b<<<ggrid, 256, 0, stream>>>(xb, meta, rowstart, dinv, aggxb);
  k_hw_mfma0<<<hwgrid, 256, 0, stream>>>((unsigned short*)aggxb, wt0,
                                         conv_b[0], (unsigned short*)h1b);
  k_gstats<<<N_GRAPHS, 512, 0, stream>>>(h1b, start, gn_w[0], gn_b[0],
                                         gn_ms[0], A0, B0);
  // layer 1
  k_hw_mfma<<<hwgrid, 256, 0, stream>>>(h1b, wt1, batch, A0, B0, dinv,
                                        (unsigned short*)hwb);
  k_gatherb<<<ggrid, 256, 0, stream>>>(hwb, meta, rowstart, dinv, conv_b[1],
                                       agg1b);
  k_gstats<<<N_GRAPHS, 512, 0, stream>>>(agg1b, start, gn_w[1], gn_b[1],
                                         gn_ms[1], A1, B1);
  // layer 2
  k_hw_mfma<<<hwgrid, 256, 0, stream>>>(agg1b, wt2, batch, A1, B1, dinv,
                                        (unsigned short*)hwb);
  k_gatherb<<<ggrid, 256, 0, stream>>>(hwb, meta, rowstart, dinv, conv_b[2],
                                       agg2b);
  k_gstats<<<N_GRAPHS, 512, 0, stream>>>(agg2b, start, gn_w[2], gn_b[2],
                                         gn_ms[2], A2, B2);

  k_pool<<<N_GRAPHS, 512, 0, stream>>>(agg2b, start, A2, B2, pooled);
  k_head<<<N_GRAPHS, 256, 0, stream>>>(pooled, lin_w0, lin_b0, bn_g0, bn_b0,
                                       lin_w1, lin_b1, bn_g1, bn_b1, out_w,
                                       out_b, (float*)d_out);
}

// Round 15
// 489.374 us; speedup vs baseline: 1.6601x; 1.0234x over previous
//
#include <hip/hip_runtime.h>

#define N_NODES 100000
#define N_EDGES 1600000
#define N_GRAPHS 256
#define EPS 1e-5f

#define NBUCK 1024            // buckets = tgt >> 7 (782 used)
#define NUSED 782
#define NBLK 256              // scatter blocks
#define EPB (N_EDGES / NBLK)  // 6250 edges per scatter block

// k_prep block ranges
#define WB 128   // W1/W2 transpose
#define W0B 32   // W0 transpose
#define SB 2     // graph starts
#define PREP_BLOCKS (WB + W0B + SB + NBLK)

typedef __attribute__((ext_vector_type(8))) short bfrag8;  // 8 bf16
typedef __attribute__((ext_vector_type(4))) float facc4;   // 4 f32 acc

__device__ __forceinline__ void fma4(float4& a, float s, const float4& w) {
  a.x += s * w.x; a.y += s * w.y; a.z += s * w.z; a.w += s * w.w;
}

__device__ __forceinline__ unsigned short f2bf(float f) {
  union { float f; unsigned u; } x;
  x.f = f;
  unsigned r = x.u + 0x7FFF + ((x.u >> 16) & 1);  // RNE
  return (unsigned short)(r >> 16);
}
__device__ __forceinline__ unsigned packbf(float a, float b) {
  return (unsigned)f2bf(a) | ((unsigned)f2bf(b) << 16);
}
__device__ __forceinline__ float4 bf4(unsigned lo, unsigned hi) {
  union { unsigned u; float f; } a, b, c, d;
  a.u = lo << 16;
  b.u = lo & 0xFFFF0000u;
  c.u = hi << 16;
  d.u = hi & 0xFFFF0000u;
  return make_float4(a.f, b.f, c.f, d.f);
}
__device__ __forceinline__ float bfat(const unsigned* tb, int idx) {
  unsigned u = tb[idx >> 1];
  union { unsigned u; float f; } v;
  v.u = (idx & 1) ? (u & 0xFFFF0000u) : (u << 16);
  return v.f;
}

// ---------------------------------------------------------------------------
// Prep: W transposes, graph starts, per-scatter-block bucket histogram
// (+ per-bucket totals into bcnt).
// ---------------------------------------------------------------------------
__global__ __launch_bounds__(256) void k_prep(
    const float* __restrict__ cw1, const float* __restrict__ cw2,
    unsigned short* __restrict__ wt1, unsigned short* __restrict__ wt2,
    const float* __restrict__ cw0, unsigned short* __restrict__ wt0,
    const int* __restrict__ batch, int* __restrict__ start,
    const int* __restrict__ tgt, int* __restrict__ hists,
    int* __restrict__ bcnt) {
  __shared__ int h[NBUCK];
  const int b = blockIdx.x;
  const int t = threadIdx.x;
  if (b < WB) {
    int half = b >> 6;              // 0: w1, 1: w2
    int id = (b & 63) * 256 + t;    // 0..16383
    const float* w = half ? cw2 : cw1;
    unsigned short* o = half ? wt2 : wt1;
    int n = id >> 7, k = id & 127;
    o[n * 128 + k] = f2bf(w[k * 128 + n]);
  } else if (b < WB + W0B) {
    int id = (b - WB) * 256 + t;
    if (id >= 8192) return;
    int n = id >> 6, k = id & 63;
    wt0[n * 64 + k] = f2bf(cw0[k * 128 + n]);
  } else if (b < WB + W0B + SB) {
    int g = (b - WB - W0B) * 256 + t;
    if (g > N_GRAPHS) return;
    int lo = 0, hi = N_NODES;
    while (lo < hi) {
      int mid = (lo + hi) >> 1;
      if (batch[mid] < g) lo = mid + 1; else hi = mid;
    }
    start[g] = lo;
  } else {
    const int blk = b - WB - W0B - SB;  // 0..NBLK-1
    for (int i = t; i < NBUCK; i += 256) h[i] = 0;
    __syncthreads();
    const int s = blk * EPB, e = s + EPB;
    for (int j = s + t; j < e; j += 256) atomicAdd(&h[tgt[j] >> 7], 1);
    __syncthreads();
    for (int i = t; i < NBUCK; i += 256) {
      int v = h[i];
      hists[blk * NBUCK + i] = v;
      if (v) atomicAdd(&bcnt[i], v);
    }
  }
}

// Bucket scan: 1 block x 1024. bcnt -> exclusive bbase.
__global__ __launch_bounds__(1024) void k_bscan(const int* __restrict__ bcnt,
                                                int* __restrict__ bbase) {
  __shared__ int s[NBUCK];
  const int b = threadIdx.x;
  int v = bcnt[b];
  s[b] = v;
  __syncthreads();
  for (int off = 1; off < NBUCK; off <<= 1) {
    int u = (b >= off) ? s[b - off] : 0;
    __syncthreads();
    s[b] += u;
    __syncthreads();
  }
  bbase[b] = s[b] - v;  // exclusive
  if (b == NBUCK - 1) bbase[NBUCK] = N_EDGES;
}

// Per-(bucket,block) cursor bases: one block per bucket; LDS scan over the
// NBLK scatter blocks; cursor stored bucket-major (coalesced writes).
__global__ __launch_bounds__(NBLK) void k_cursors(const int* __restrict__ hists,
                                                  const int* __restrict__ bbase,
                                                  int* __restrict__ cursor) {
  __shared__ int s[NBLK];
  const int b = blockIdx.x;   // bucket
  const int k = threadIdx.x;  // scatter block
  int v = hists[k * NBUCK + b];
  s[k] = v;
  __syncthreads();
  for (int off = 1; off < NBLK; off <<= 1) {
    int u = (k >= off) ? s[k - off] : 0;
    __syncthreads();
    s[k] += u;
    __syncthreads();
  }
  cursor[b * NBLK + k] = bbase[b] + s[k] - v;
}

// ---------------------------------------------------------------------------
// Fused edge-MLP + bucket scatter (LDS cursors, contiguous destinations):
// mb[pos] = {bits(ew), src | (tgt&127)<<25}.
// ---------------------------------------------------------------------------
__global__ __launch_bounds__(256) void k_scatter(
    const float* __restrict__ ea, const float* __restrict__ w1,
    const float* __restrict__ b1, const float* __restrict__ w2,
    const float* __restrict__ b2, const int* __restrict__ src,
    const int* __restrict__ tgt, const int* __restrict__ cursor,
    uint2* __restrict__ mb) {
  __shared__ float W1[128], B1[16], W2[16];
  __shared__ int cur[NBUCK];
  const int blk = blockIdx.x, t = threadIdx.x;
  if (t < 128) W1[t] = w1[t];
  if (t < 16) { B1[t] = b1[t]; W2[t] = w2[t]; }
  for (int i = t; i < NUSED; i += 256) cur[i] = cursor[i * NBLK + blk];
  __syncthreads();
  const int s = blk * EPB, e = s + EPB;
  for (int j = s + t; j < e; j += 256) {
    const float4* ap = (const float4*)(ea + (size_t)j * 8);
    float4 a0 = ap[0], a1 = ap[1];
    float a[8] = {a0.x, a0.y, a0.z, a0.w, a1.x, a1.y, a1.z, a1.w};
    float out = b2[0];
#pragma unroll
    for (int i = 0; i < 16; ++i) {
      float h = B1[i];
#pragma unroll
      for (int jj = 0; jj < 8; ++jj) h += a[jj] * W1[i * 8 + jj];
      out += fmaxf(h, 0.f) * W2[i];
    }
    int d = tgt[j];
    int bin = d >> 7;
    int pos = atomicAdd(&cur[bin], 1);
    union { float f; unsigned u; } w;
    w.f = out;
    mb[pos] = make_uint2(w.u, (unsigned)src[j] | ((unsigned)(d & 127) << 25));
  }
}

// ---------------------------------------------------------------------------
// Bucket -> CSR + dinv + x-convert: one block per bucket (=128 nodes).
// Pass 1 bins counts AND float deg sums; scan -> rowstart + dinv;
// pass 2 places meta; pass 3 converts this block's x rows to bf16(dinv*x).
// ---------------------------------------------------------------------------
__global__ __launch_bounds__(256) void k_csr(
    const uint2* __restrict__ mb, const int* __restrict__ bbase,
    const float* __restrict__ x, uint2* __restrict__ meta,
    int* __restrict__ rowstart, float* __restrict__ dinv,
    unsigned* __restrict__ xb) {
  __shared__ int hist[128];
  __shared__ float degf[128];
  __shared__ int cur[128];
  __shared__ float dls[128];
  const int b = blockIdx.x;
  const int t = threadIdx.x;
  const int s = bbase[b], e = bbase[b + 1];
  if (t < 128) { hist[t] = 0; degf[t] = 0.f; }
  __syncthreads();
  for (int j = s + t; j < e; j += 256) {
    uint2 m = mb[j];
    int bin = m.y >> 25;
    atomicAdd(&hist[bin], 1);
    union { unsigned u; float f; } w;
    w.u = m.x;
    atomicAdd(&degf[bin], w.f);
  }
  __syncthreads();
  int own = (t < 128) ? hist[t] : 0;
  for (int off = 1; off < 128; off <<= 1) {
    int u = (t >= off && t < 128) ? hist[t - off] : 0;
    __syncthreads();
    if (t < 128) hist[t] += u;
    __syncthreads();
  }
  if (t < 128) {
    int excl = hist[t] - own;
    int node = b * 128 + t;
    if (node <= N_NODES) rowstart[node] = s + excl;
    float dv = 0.f;
    if (node < N_NODES) {
      float d = 1.f + degf[t];
      dv = d > 0.f ? rsqrtf(d) : 0.f;
      dinv[node] = dv;
    }
    dls[t] = dv;
    cur[t] = s + excl;
  }
  __syncthreads();
  for (int j = s + t; j < e; j += 256) {
    uint2 m = mb[j];
    int bin = m.y >> 25;
    int pos = atomicAdd(&cur[bin], 1);
    meta[pos] = make_uint2(m.x, m.y & 0x1FFFFFFu);
  }
  // x -> bf16(dinv*x) for this block's 128 nodes (64 ch each)
  {
    const int ln = t >> 1, half = t & 1;
    const int node = b * 128 + ln;
    if (node < N_NODES) {
      float dv = dls[ln];
      const float* px = x + (size_t)node * 64 + half * 32;
#pragma unroll
      for (int c8 = 0; c8 < 4; ++c8) {
        float4 a = *(const float4*)(px + c8 * 8);
        float4 bb = *(const float4*)(px + c8 * 8 + 4);
        uint4 o;
        o.x = packbf(dv * a.x, dv * a.y);
        o.y = packbf(dv * a.z, dv * a.w);
        o.z = packbf(dv * bb.x, dv * bb.y);
        o.w = packbf(dv * bb.z, dv * bb.w);
        *(uint4*)&xb[(size_t)node * 32 + half * 16 + c8 * 4] = o;
      }
    }
  }
}

// ---------------------------------------------------------------------------
// 64-ch CSR gather on pre-scaled bf16 x' (= dinv*x).
// ---------------------------------------------------------------------------
__global__ __launch_bounds__(256) void k_gather64b(
    const unsigned* __restrict__ xb, const uint2* __restrict__ meta,
    const int* __restrict__ rowstart, const float* __restrict__ dinv,
    unsigned* __restrict__ aggxb) {
  const int t = threadIdx.x;
  const int n = blockIdx.x * 4 + (t >> 6);
  if (n >= N_NODES) return;
  const unsigned lane = t & 63;
  const unsigned q = lane >> 3;   // edge slot 0..7
  const unsigned cl = lane & 7;   // uint4 group (8 ch) over 64 ch
  const int rs = rowstart[n], re = rowstart[n + 1];
  const uint4* x4 = (const uint4*)xb;
  float4 lo0 = make_float4(0.f, 0.f, 0.f, 0.f), hi0 = lo0;
  float4 lo1 = lo0, hi1 = lo0;
  int j = rs;
  for (; j + 16 <= re; j += 16) {
    uint2 m0 = meta[j + q], m1 = meta[j + 8 + q];
    union { unsigned u; float f; } w0, w1;
    w0.u = m0.x; w1.u = m1.x;
    uint4 v0 = x4[(m0.y << 3) + cl];
    uint4 v1 = x4[(m1.y << 3) + cl];
    fma4(lo0, w0.f, bf4(v0.x, v0.y));
    fma4(hi0, w0.f, bf4(v0.z, v0.w));
    fma4(lo1, w1.f, bf4(v1.x, v1.y));
    fma4(hi1, w1.f, bf4(v1.z, v1.w));
  }
  for (; j + 8 <= re; j += 8) {
    uint2 m0 = meta[j + q];
    union { unsigned u; float f; } w0;
    w0.u = m0.x;
    uint4 v0 = x4[(m0.y << 3) + cl];
    fma4(lo0, w0.f, bf4(v0.x, v0.y));
    fma4(hi0, w0.f, bf4(v0.z, v0.w));
  }
  if (j + (int)q < re) {
    uint2 m0 = meta[j + q];
    union { unsigned u; float f; } w0;
    w0.u = m0.x;
    uint4 v0 = x4[(m0.y << 3) + cl];
    fma4(lo1, w0.f, bf4(v0.x, v0.y));
    fma4(hi1, w0.f, bf4(v0.z, v0.w));
  }
  lo0.x += lo1.x; lo0.y += lo1.y; lo0.z += lo1.z; lo0.w += lo1.w;
  hi0.x += hi1.x; hi0.y += hi1.y; hi0.z += hi1.z; hi0.w += hi1.w;
#pragma unroll
  for (int m = 8; m <= 32; m <<= 1) {
    lo0.x += __shfl_xor(lo0.x, m);
    lo0.y += __shfl_xor(lo0.y, m);
    lo0.z += __shfl_xor(lo0.z, m);
    lo0.w += __shfl_xor(lo0.w, m);
    hi0.x += __shfl_xor(hi0.x, m);
    hi0.y += __shfl_xor(hi0.y, m);
    hi0.z += __shfl_xor(hi0.z, m);
    hi0.w += __shfl_xor(hi0.w, m);
  }
  if (q == 0) {
    float dv = dinv[n];
    uint4 sv = x4[((unsigned)n << 3) + cl];
    float4 slo = bf4(sv.x, sv.y), shi = bf4(sv.z, sv.w);
    uint4 o;
    o.x = packbf(dv * (lo0.x + slo.x), dv * (lo0.y + slo.y));
    o.y = packbf(dv * (lo0.z + slo.z), dv * (lo0.w + slo.w));
    o.z = packbf(dv * (hi0.x + shi.x), dv * (hi0.y + shi.y));
    o.w = packbf(dv * (hi0.z + shi.z), dv * (hi0.w + shi.w));
    ((uint4*)aggxb)[((unsigned)n << 3) + cl] = o;
  }
}

// ---------------------------------------------------------------------------
// Layer-0 MFMA GEMM: h1b = bf16( aggxb @ W0 + b0 ).  CIN=64.
// ---------------------------------------------------------------------------
__global__ __launch_bounds__(256) void k_hw_mfma0(
    const unsigned short* __restrict__ aggxb,
    const unsigned short* __restrict__ wt0, const float* __restrict__ bias,
    unsigned short* __restrict__ h1b) {
  __shared__ unsigned short Asb[64][72];
  __shared__ unsigned short Wsb[128][72];
  const int t = threadIdx.x;
  const int base = blockIdx.x * 64;

  for (int i = t; i < 1024; i += 256) {
    int nr = i >> 3, k8 = (i & 7) * 8;
    *(uint4*)&Wsb[nr][k8] = *(const uint4*)&wt0[nr * 64 + k8];
  }
  {
    const int ln = t >> 2;
    const int kp = (t & 3) * 16;
    const int n = base + ln;
    if (n < N_NODES) {
      *(uint4*)&Asb[ln][kp] = *(const uint4*)&aggxb[(size_t)n * 64 + kp];
      *(uint4*)&Asb[ln][kp + 8] = *(const uint4*)&aggxb[(size_t)n * 64 + kp + 8];
    } else {
      uint4 z = make_uint4(0, 0, 0, 0);
      *(uint4*)&Asb[ln][kp] = z;
      *(uint4*)&Asb[ln][kp + 8] = z;
    }
  }
  __syncthreads();

  const int wv = t >> 6;
  const int lr = t & 15;
  const int lk = (t >> 4) & 3;
  const int m0 = wv * 16;

  bfrag8 af[2];
#pragma unroll
  for (int kc = 0; kc < 2; ++kc)
    af[kc] = *(const bfrag8*)&Asb[m0 + lr][kc * 32 + lk * 8];

#pragma unroll
  for (int nt = 0; nt < 8; ++nt) {
    facc4 c = {0.f, 0.f, 0.f, 0.f};
#pragma unroll
    for (int kc = 0; kc < 2; ++kc) {
      bfrag8 bf = *(const bfrag8*)&Wsb[nt * 16 + lr][kc * 32 + lk * 8];
      c = __builtin_amdgcn_mfma_f32_16x16x32_bf16(af[kc], bf, c, 0, 0, 0);
    }
    int col = nt * 16 + lr;
    float bv = bias[col];
#pragma unroll
    for (int r = 0; r < 4; ++r) {
      int n = base + m0 + lk * 4 + r;
      if (n < N_NODES) h1b[(size_t)n * 128 + col] = f2bf(c[r] + bv);
    }
  }
}

// ---------------------------------------------------------------------------
// Layers 1-2 MFMA GEMM: hwb = bf16( dinv[n] * (relu(A*h+B) @ W) ).
// ---------------------------------------------------------------------------
__global__ __launch_bounds__(256) void k_hw_mfma(
    const unsigned* __restrict__ hb, const unsigned short* __restrict__ wt,
    const int* __restrict__ batch, const float* __restrict__ An,
    const float* __restrict__ Bn, const float* __restrict__ dinv,
    unsigned short* __restrict__ hwb) {
  __shared__ unsigned short Asb[64][136];
  __shared__ unsigned short Wsb[128][136];
  const int t = threadIdx.x;
  const int base = blockIdx.x * 64;

  for (int i = t; i < 2048; i += 256) {
    int nr = i >> 4, k8 = (i & 15) * 8;
    *(uint4*)&Wsb[nr][k8] = *(const uint4*)&wt[nr * 128 + k8];
  }
  {
    const int ln = t >> 2;
    const int cg = (t & 3) * 32;
    const int n = base + ln;
    if (n < N_NODES) {
      const int g = batch[n];
      const uint4* hp = (const uint4*)(hb + (size_t)n * 64);
      const float* Ap = An + (size_t)g * 128;
      const float* Bp = Bn + (size_t)g * 128;
#pragma unroll
      for (int qq = 0; qq < 4; ++qq) {
        int c = cg + qq * 8;
        uint4 v = hp[(t & 3) * 4 + qq];
        float4 lo = bf4(v.x, v.y);
        float4 hi = bf4(v.z, v.w);
        float4 Alo = *(const float4*)&Ap[c], Blo = *(const float4*)&Bp[c];
        float4 Ahi = *(const float4*)&Ap[c + 4], Bhi = *(const float4*)&Bp[c + 4];
        uint4 o;
        o.x = packbf(fmaxf(Alo.x * lo.x + Blo.x, 0.f),
                     fmaxf(Alo.y * lo.y + Blo.y, 0.f));
        o.y = packbf(fmaxf(Alo.z * lo.z + Blo.z, 0.f),
                     fmaxf(Alo.w * lo.w + Blo.w, 0.f));
        o.z = packbf(fmaxf(Ahi.x * hi.x + Bhi.x, 0.f),
                     fmaxf(Ahi.y * hi.y + Bhi.y, 0.f));
        o.w = packbf(fmaxf(Ahi.z * hi.z + Bhi.z, 0.f),
                     fmaxf(Ahi.w * hi.w + Bhi.w, 0.f));
        *(uint4*)&Asb[ln][c] = o;
      }
    } else {
      uint4 z = make_uint4(0, 0, 0, 0);
#pragma unroll
      for (int qq = 0; qq < 4; ++qq) *(uint4*)&Asb[ln][cg + qq * 8] = z;
    }
  }
  __syncthreads();

  const int wv = t >> 6;
  const int lr = t & 15;
  const int lk = (t >> 4) & 3;
  const int m0 = wv * 16;

  bfrag8 af[4];
#pragma unroll
  for (int kc = 0; kc < 4; ++kc)
    af[kc] = *(const bfrag8*)&Asb[m0 + lr][kc * 32 + lk * 8];

  float dv[4];
#pragma unroll
  for (int r = 0; r < 4; ++r) {
    int n = base + m0 + lk * 4 + r;
    dv[r] = (n < N_NODES) ? dinv[n] : 0.f;
  }

#pragma unroll
  for (int nt = 0; nt < 8; ++nt) {
    facc4 c = {0.f, 0.f, 0.f, 0.f};
#pragma unroll
    for (int kc = 0; kc < 4; ++kc) {
      bfrag8 bf = *(const bfrag8*)&Wsb[nt * 16 + lr][kc * 32 + lk * 8];
      c = __builtin_amdgcn_mfma_f32_16x16x32_bf16(af[kc], bf, c, 0, 0, 0);
    }
    int col = nt * 16 + lr;
#pragma unroll
    for (int r = 0; r < 4; ++r) {
      int n = base + m0 + lk * 4 + r;
      if (n < N_NODES) hwb[(size_t)n * 128 + col] = f2bf(dv[r] * c[r]);
    }
  }
}

// ---------------------------------------------------------------------------
// 128-ch CSR gather on dinv-scaled bf16 table.
// ---------------------------------------------------------------------------
__global__ __launch_bounds__(256) void k_gatherb(
    const unsigned* __restrict__ hwb, const uint2* __restrict__ meta,
    const int* __restrict__ rowstart, const float* __restrict__ dinv,
    const float* __restrict__ bias, unsigned* __restrict__ aggb) {
  const int t = threadIdx.x;
  const int n = blockIdx.x * 4 + (t >> 6);
  if (n >= N_NODES) return;
  const unsigned lane = t & 63;
  const unsigned q = lane >> 4;   // edge slot 0..3
  const unsigned cl = lane & 15;  // uint4 group (8 ch) over 128 ch
  const int rs = rowstart[n], re = rowstart[n + 1];
  const uint4* hb4 = (const uint4*)hwb;
  float4 lo0 = make_float4(0.f, 0.f, 0.f, 0.f), hi0 = lo0;
  float4 lo1 = lo0, hi1 = lo0;
  int j = rs;
  for (; j + 8 <= re; j += 8) {
    uint2 m0 = meta[j + q], m1 = meta[j + 4 + q];
    union { unsigned u; float f; } w0, w1;
    w0.u = m0.x; w1.u = m1.x;
    uint4 v0 = hb4[(m0.y << 4) + cl];
    uint4 v1 = hb4[(m1.y << 4) + cl];
    fma4(lo0, w0.f, bf4(v0.x, v0.y));
    fma4(hi0, w0.f, bf4(v0.z, v0.w));
    fma4(lo1, w1.f, bf4(v1.x, v1.y));
    fma4(hi1, w1.f, bf4(v1.z, v1.w));
  }
  for (; j + 4 <= re; j += 4) {
    uint2 m0 = meta[j + q];
    union { unsigned u; float f; } w0;
    w0.u = m0.x;
    uint4 v0 = hb4[(m0.y << 4) + cl];
    fma4(lo0, w0.f, bf4(v0.x, v0.y));
    fma4(hi0, w0.f, bf4(v0.z, v0.w));
  }
  if (j + (int)q < re) {
    uint2 m0 = meta[j + q];
    union { unsigned u; float f; } w0;
    w0.u = m0.x;
    uint4 v0 = hb4[(m0.y << 4) + cl];
    fma4(lo1, w0.f, bf4(v0.x, v0.y));
    fma4(hi1, w0.f, bf4(v0.z, v0.w));
  }
  lo0.x += lo1.x; lo0.y += lo1.y; lo0.z += lo1.z; lo0.w += lo1.w;
  hi0.x += hi1.x; hi0.y += hi1.y; hi0.z += hi1.z; hi0.w += hi1.w;
#pragma unroll
  for (int m = 16; m <= 32; m <<= 1) {
    lo0.x += __shfl_xor(lo0.x, m);
    lo0.y += __shfl_xor(lo0.y, m);
    lo0.z += __shfl_xor(lo0.z, m);
    lo0.w += __shfl_xor(lo0.w, m);
    hi0.x += __shfl_xor(hi0.x, m);
    hi0.y += __shfl_xor(hi0.y, m);
    hi0.z += __shfl_xor(hi0.z, m);
    hi0.w += __shfl_xor(hi0.w, m);
  }
  if (q == 0) {
    float dv = dinv[n];
    uint4 sv = hb4[((unsigned)n << 4) + cl];
    float4 slo = bf4(sv.x, sv.y), shi = bf4(sv.z, sv.w);
    float4 blo = *(const float4*)&bias[cl * 8];
    float4 bhi = *(const float4*)&bias[cl * 8 + 4];
    uint4 o;
    o.x = packbf(dv * (lo0.x + slo.x) + blo.x, dv * (lo0.y + slo.y) + blo.y);
    o.y = packbf(dv * (lo0.z + slo.z) + blo.z, dv * (lo0.w + slo.w) + blo.w);
    o.z = packbf(dv * (hi0.x + shi.x) + bhi.x, dv * (hi0.y + shi.y) + bhi.y);
    o.w = packbf(dv * (hi0.z + shi.z) + bhi.z, dv * (hi0.w + shi.w) + bhi.w);
    ((uint4*)aggb)[((unsigned)n << 4) + cl] = o;
  }
}

// ---------------------------------------------------------------------------
// GraphNorm stats on bf16 table (layers 0,1).
// ---------------------------------------------------------------------------
__global__ __launch_bounds__(512) void k_gstats(
    const unsigned* __restrict__ hb, const int* __restrict__ start,
    const float* __restrict__ gw, const float* __restrict__ gb,
    const float* __restrict__ gms, float* __restrict__ An,
    float* __restrict__ Bn) {
  int g = blockIdx.x;
  int s = start[g], e = start[g + 1];
  int t = threadIdx.x, p = t >> 7, c = t & 127;
  float sum = 0.f, sq = 0.f;
  for (int n = s + p; n < e; n += 4) {
    float v = bfat(hb + (size_t)n * 64, c);
    sum += v;
    sq += v * v;
  }
  __shared__ float S[4][128], Q[4][128];
  S[p][c] = sum;
  Q[p][c] = sq;
  __syncthreads();
  if (t < 128) {
    float cnt = (float)max(e - s, 1);
    float mean = (S[0][t] + S[1][t] + S[2][t] + S[3][t]) / cnt;
    float e2 = (Q[0][t] + Q[1][t] + Q[2][t] + Q[3][t]) / cnt;
    float ms = gms[t];
    float var = fmaxf(e2 - ms * (2.f - ms) * mean * mean, 0.f);
    float scale = gw[t] / sqrtf(var + EPS);
    An[(size_t)g * 128 + t] = scale;
    Bn[(size_t)g * 128 + t] = gb[t] - scale * ms * mean;
  }
}

// ---------------------------------------------------------------------------
// Layer-2 GraphNorm stats + fused mean-pool of relu(A*h+B).
// ---------------------------------------------------------------------------
__global__ __launch_bounds__(512) void k_gstats_pool(
    const unsigned* __restrict__ hb, const int* __restrict__ start,
    const float* __restrict__ gw, const float* __restrict__ gb,
    const float* __restrict__ gms, float* __restrict__ pooled) {
  int g = blockIdx.x;
  int s = start[g], e = start[g + 1];
  int t = threadIdx.x, p = t >> 7, c = t & 127;
  float sum = 0.f, sq = 0.f;
  for (int n = s + p; n < e; n += 4) {
    float v = bfat(hb + (size_t)n * 64, c);
    sum += v;
    sq += v * v;
  }
  __shared__ float S[4][128], Q[4][128], Af[128], Bf[128];
  S[p][c] = sum;
  Q[p][c] = sq;
  __syncthreads();
  if (t < 128) {
    float cnt = (float)max(e - s, 1);
    float mean = (S[0][t] + S[1][t] + S[2][t] + S[3][t]) / cnt;
    float e2 = (Q[0][t] + Q[1][t] + Q[2][t] + Q[3][t]) / cnt;
    float ms = gms[t];
    float var = fmaxf(e2 - ms * (2.f - ms) * mean * mean, 0.f);
    float scale = gw[t] / sqrtf(var + EPS);
    Af[t] = scale;
    Bf[t] = gb[t] - scale * ms * mean;
  }
  __syncthreads();
  float A = Af[c], B = Bf[c];
  float psum = 0.f;
  for (int n = s + p; n < e; n += 4)
    psum += fmaxf(A * bfat(hb + (size_t)n * 64, c) + B, 0.f);
  __syncthreads();
  S[p][c] = psum;
  __syncthreads();
  if (t < 128) {
    float cnt = (float)max(e - s, 1);
    pooled[g * 128 + t] = (S[0][t] + S[1][t] + S[2][t] + S[3][t]) / cnt;
  }
}

// MLP head: 128 ->256 (BN,ReLU) ->128 (BN,ReLU) ->1; writes out[g] and h2.
__global__ __launch_bounds__(256) void k_head(
    const float* __restrict__ pooled, const float* __restrict__ w0,
    const float* __restrict__ b0, const float* __restrict__ g0,
    const float* __restrict__ bb0, const float* __restrict__ w1,
    const float* __restrict__ b1, const float* __restrict__ g1,
    const float* __restrict__ bb1, const float* __restrict__ ow,
    const float* __restrict__ ob, float* __restrict__ out) {
  __shared__ float p[128], h1[256], h2[128];
  int g = blockIdx.x, t = threadIdx.x;
  const float inv = 1.0f / sqrtf(1.0f + EPS);
  if (t < 128) p[t] = pooled[g * 128 + t];
  __syncthreads();
  {
    float acc = b0[t];
#pragma unroll 8
    for (int k = 0; k < 128; ++k) acc += p[k] * w0[k * 256 + t];
    h1[t] = fmaxf(acc * inv * g0[t] + bb0[t], 0.f);
  }
  __syncthreads();
  if (t < 128) {
    float acc = b1[t];
#pragma unroll 8
    for (int k = 0; k < 256; ++k) acc += h1[k] * w1[k * 128 + t];
    float v = fmaxf(acc * inv * g1[t] + bb1[t], 0.f);
    h2[t] = v;
    out[N_GRAPHS + g * 128 + t] = v;
  }
  __syncthreads();
  if (t < 64) {
    float v = h2[t] * ow[t] + h2[t + 64] * ow[t + 64];
#pragma unroll
    for (int off = 32; off; off >>= 1) v += __shfl_down(v, off);
    if (t == 0) out[g] = v + ob[0];
  }
}

// ---------------------------------------------------------------------------
extern "C" void kernel_launch(void* const* d_in, const int* in_sizes, int n_in,
                              void* d_out, int out_size, void* d_ws,
                              size_t ws_size, hipStream_t stream) {
  const float* x = (const float*)d_in[0];
  const float* edge_attr = (const float*)d_in[1];
  const float* em_w1 = (const float*)d_in[2];
  const float* em_b1 = (const float*)d_in[3];
  const float* em_w2 = (const float*)d_in[4];
  const float* em_b2 = (const float*)d_in[5];
  const float* conv_w[3] = {(const float*)d_in[6], (const float*)d_in[8],
                            (const float*)d_in[10]};
  const float* conv_b[3] = {(const float*)d_in[7], (const float*)d_in[9],
                            (const float*)d_in[11]};
  const float* gn_w[3] = {(const float*)d_in[12], (const float*)d_in[15],
                          (const float*)d_in[18]};
  const float* gn_b[3] = {(const float*)d_in[13], (const float*)d_in[16],
                          (const float*)d_in[19]};
  const float* gn_ms[3] = {(const float*)d_in[14], (const float*)d_in[17],
                           (const float*)d_in[20]};
  const float* lin_w0 = (const float*)d_in[21];
  const float* lin_b0 = (const float*)d_in[22];
  const float* bn_g0 = (const float*)d_in[23];
  const float* bn_b0 = (const float*)d_in[24];
  const float* lin_w1 = (const float*)d_in[25];
  const float* lin_b1 = (const float*)d_in[26];
  const float* bn_g1 = (const float*)d_in[27];
  const float* bn_b1 = (const float*)d_in[28];
  const float* out_w = (const float*)d_in[29];
  const float* out_b = (const float*)d_in[30];
  const int* edge_index = (const int*)d_in[31];
  const int* batch = (const int*)d_in[32];
  const int* src = edge_index;
  const int* tgt = edge_index + N_EDGES;

  char* w = (char*)d_ws;
  size_t off = 0;
  auto carve = [&](size_t bytes) {
    void* p = w + off;
    off = (off + bytes + 511) & ~(size_t)511;
    return p;
  };
  float* dinv = (float*)carve((size_t)N_NODES * 4);
  int* rowstart = (int*)carve((size_t)(N_NODES + 1) * 4);
  int* hists = (int*)carve((size_t)NBLK * NBUCK * 4);
  int* cursor = (int*)carve((size_t)NBUCK * NBLK * 4);
  int* bcnt = (int*)carve((size_t)NBUCK * 4);
  int* bbase = (int*)carve((size_t)(NBUCK + 1) * 4);
  uint2* mb = (uint2*)carve((size_t)N_EDGES * 8);
  uint2* meta = (uint2*)carve((size_t)N_EDGES * 8);
  int* start = (int*)carve((N_GRAPHS + 1) * 4);
  float* AB = (float*)carve((size_t)4 * N_GRAPHS * 128 * 4);
  unsigned* xb = (unsigned*)carve((size_t)N_NODES * 64 * 2);
  unsigned* aggxb = (unsigned*)carve((size_t)N_NODES * 64 * 2);
  unsigned* h1b = (unsigned*)carve((size_t)N_NODES * 128 * 2);
  unsigned* hwb = (unsigned*)carve((size_t)N_NODES * 128 * 2);
  unsigned* agg1b = (unsigned*)carve((size_t)N_NODES * 128 * 2);
  unsigned* agg2b = (unsigned*)carve((size_t)N_NODES * 128 * 2);
  unsigned short* wt0 = (unsigned short*)carve((size_t)128 * 64 * 2);
  unsigned short* wt1 = (unsigned short*)carve((size_t)128 * 128 * 2);
  unsigned short* wt2 = (unsigned short*)carve((size_t)128 * 128 * 2);
  float* pooled = (float*)carve((size_t)N_GRAPHS * 128 * 4);

  float* A0 = AB, *B0 = AB + N_GRAPHS * 128;
  float* A1 = AB + 2 * N_GRAPHS * 128, *B1 = AB + 3 * N_GRAPHS * 128;

  hipMemsetAsync(bcnt, 0, (size_t)NBUCK * 4, stream);

  k_prep<<<PREP_BLOCKS, 256, 0, stream>>>(conv_w[1], conv_w[2], wt1, wt2,
                                          conv_w[0], wt0, batch, start, tgt,
                                          hists, bcnt);
  k_bscan<<<1, 1024, 0, stream>>>(bcnt, bbase);
  k_cursors<<<NUSED, NBLK, 0, stream>>>(hists, bbase, cursor);
  k_scatter<<<NBLK, 256, 0, stream>>>(edge_attr, em_w1, em_b1, em_w2, em_b2,
                                      src, tgt, cursor, mb);
  k_csr<<<NUSED, 256, 0, stream>>>(mb, bbase, x, meta, rowstart, dinv, xb);

  const int ggrid = (N_NODES + 3) / 4;
  const int hwgrid = (N_NODES + 63) / 64;

  // layer 0: aggregate-first (bf16, dinv folded), MFMA GEMM + bias -> h1b.
  k_gather64b<<<ggrid, 256, 0, stream>>>(xb, meta, rowstart, dinv, aggxb);
  k_hw_mfma0<<<hwgrid, 256, 0, stream>>>((unsigned short*)aggxb, wt0,
                                         conv_b[0], (unsigned short*)h1b);
  k_gstats<<<N_GRAPHS, 512, 0, stream>>>(h1b, start, gn_w[0], gn_b[0],
                                         gn_ms[0], A0, B0);
  // layer 1
  k_hw_mfma<<<hwgrid, 256, 0, stream>>>(h1b, wt1, batch, A0, B0, dinv,
                                        (unsigned short*)hwb);
  k_gatherb<<<ggrid, 256, 0, stream>>>(hwb, meta, rowstart, dinv, conv_b[1],
                                       agg1b);
  k_gstats<<<N_GRAPHS, 512, 0, stream>>>(agg1b, start, gn_w[1], gn_b[1],
                                         gn_ms[1], A1, B1);
  // layer 2
  k_hw_mfma<<<hwgrid, 256, 0, stream>>>(agg1b, wt2, batch, A1, B1, dinv,
                                        (unsigned short*)hwb);
  k_gatherb<<<ggrid, 256, 0, stream>>>(hwb, meta, rowstart, dinv, conv_b[2],
                                       agg2b);
  k_gstats_pool<<<N_GRAPHS, 512, 0, stream>>>(agg2b, start, gn_w[2], gn_b[2],
                                              gn_ms[2], pooled);

  k_head<<<N_GRAPHS, 256, 0, stream>>>(pooled, lin_w0, lin_b0, bn_g0, bn_b0,
                                       lin_w1, lin_b1, bn_g1, bn_b1, out_w,
                                       out_b, (float*)d_out);
}

// Round 16
// 488.588 us; speedup vs baseline: 1.6628x; 1.0016x over previous
//
#include <hip/hip_runtime.h>

#define N_NODES 100000
#define N_EDGES 1600000
#define N_GRAPHS 256
#define EPS 1e-5f

#define NBUCK 1024            // buckets = tgt >> 7 (782 used)
#define NUSED 782
#define NBLK 256              // scatter blocks
#define EPB (N_EDGES / NBLK)  // 6250 edges per scatter block

// k_prep block ranges
#define WB 128   // W1/W2 transpose
#define W0B 32   // W0 transpose
#define SB 2     // graph starts
#define PREP_BLOCKS (WB + W0B + SB + NBLK)

typedef __attribute__((ext_vector_type(8))) short bfrag8;  // 8 bf16
typedef __attribute__((ext_vector_type(4))) float facc4;   // 4 f32 acc

__device__ __forceinline__ void fma4(float4& a, float s, const float4& w) {
  a.x += s * w.x; a.y += s * w.y; a.z += s * w.z; a.w += s * w.w;
}

__device__ __forceinline__ unsigned short f2bf(float f) {
  union { float f; unsigned u; } x;
  x.f = f;
  unsigned r = x.u + 0x7FFF + ((x.u >> 16) & 1);  // RNE
  return (unsigned short)(r >> 16);
}
__device__ __forceinline__ unsigned packbf(float a, float b) {
  return (unsigned)f2bf(a) | ((unsigned)f2bf(b) << 16);
}
__device__ __forceinline__ float4 bf4(unsigned lo, unsigned hi) {
  union { unsigned u; float f; } a, b, c, d;
  a.u = lo << 16;
  b.u = lo & 0xFFFF0000u;
  c.u = hi << 16;
  d.u = hi & 0xFFFF0000u;
  return make_float4(a.f, b.f, c.f, d.f);
}
__device__ __forceinline__ float bfat(const unsigned* tb, int idx) {
  unsigned u = tb[idx >> 1];
  union { unsigned u; float f; } v;
  v.u = (idx & 1) ? (u & 0xFFFF0000u) : (u << 16);
  return v.f;
}

// ---------------------------------------------------------------------------
// Prep: W transposes, graph starts, per-scatter-block bucket histogram
// (+ per-bucket totals into bcnt).
// ---------------------------------------------------------------------------
__global__ __launch_bounds__(256) void k_prep(
    const float* __restrict__ cw1, const float* __restrict__ cw2,
    unsigned short* __restrict__ wt1, unsigned short* __restrict__ wt2,
    const float* __restrict__ cw0, unsigned short* __restrict__ wt0,
    const int* __restrict__ batch, int* __restrict__ start,
    const int* __restrict__ tgt, int* __restrict__ hists,
    int* __restrict__ bcnt) {
  __shared__ int h[NBUCK];
  const int b = blockIdx.x;
  const int t = threadIdx.x;
  if (b < WB) {
    int half = b >> 6;              // 0: w1, 1: w2
    int id = (b & 63) * 256 + t;    // 0..16383
    const float* w = half ? cw2 : cw1;
    unsigned short* o = half ? wt2 : wt1;
    int n = id >> 7, k = id & 127;
    o[n * 128 + k] = f2bf(w[k * 128 + n]);
  } else if (b < WB + W0B) {
    int id = (b - WB) * 256 + t;
    if (id >= 8192) return;
    int n = id >> 6, k = id & 63;
    wt0[n * 64 + k] = f2bf(cw0[k * 128 + n]);
  } else if (b < WB + W0B + SB) {
    int g = (b - WB - W0B) * 256 + t;
    if (g > N_GRAPHS) return;
    int lo = 0, hi = N_NODES;
    while (lo < hi) {
      int mid = (lo + hi) >> 1;
      if (batch[mid] < g) lo = mid + 1; else hi = mid;
    }
    start[g] = lo;
  } else {
    const int blk = b - WB - W0B - SB;  // 0..NBLK-1
    for (int i = t; i < NBUCK; i += 256) h[i] = 0;
    __syncthreads();
    const int s = blk * EPB, e = s + EPB;
    for (int j = s + t; j < e; j += 256) atomicAdd(&h[tgt[j] >> 7], 1);
    __syncthreads();
    for (int i = t; i < NBUCK; i += 256) {
      int v = h[i];
      hists[blk * NBUCK + i] = v;
      if (v) atomicAdd(&bcnt[i], v);
    }
  }
}

// Bucket scan: 1 block x 1024. bcnt -> exclusive bbase.
__global__ __launch_bounds__(1024) void k_bscan(const int* __restrict__ bcnt,
                                                int* __restrict__ bbase) {
  __shared__ int s[NBUCK];
  const int b = threadIdx.x;
  int v = bcnt[b];
  s[b] = v;
  __syncthreads();
  for (int off = 1; off < NBUCK; off <<= 1) {
    int u = (b >= off) ? s[b - off] : 0;
    __syncthreads();
    s[b] += u;
    __syncthreads();
  }
  bbase[b] = s[b] - v;  // exclusive
  if (b == NBUCK - 1) bbase[NBUCK] = N_EDGES;
}

// Per-(bucket,block) cursor bases: one block per bucket; LDS scan over the
// NBLK scatter blocks; cursor stored bucket-major (coalesced writes).
__global__ __launch_bounds__(NBLK) void k_cursors(const int* __restrict__ hists,
                                                  const int* __restrict__ bbase,
                                                  int* __restrict__ cursor) {
  __shared__ int s[NBLK];
  const int b = blockIdx.x;   // bucket
  const int k = threadIdx.x;  // scatter block
  int v = hists[k * NBUCK + b];
  s[k] = v;
  __syncthreads();
  for (int off = 1; off < NBLK; off <<= 1) {
    int u = (k >= off) ? s[k - off] : 0;
    __syncthreads();
    s[k] += u;
    __syncthreads();
  }
  cursor[b * NBLK + k] = bbase[b] + s[k] - v;
}

// ---------------------------------------------------------------------------
// Fused edge-MLP + bucket scatter (LDS cursors, contiguous destinations):
// mb[pos] = {bits(ew), src | (tgt&127)<<25}.
// ---------------------------------------------------------------------------
__global__ __launch_bounds__(256) void k_scatter(
    const float* __restrict__ ea, const float* __restrict__ w1,
    const float* __restrict__ b1, const float* __restrict__ w2,
    const float* __restrict__ b2, const int* __restrict__ src,
    const int* __restrict__ tgt, const int* __restrict__ cursor,
    uint2* __restrict__ mb) {
  __shared__ float W1[128], B1[16], W2[16];
  __shared__ int cur[NBUCK];
  const int blk = blockIdx.x, t = threadIdx.x;
  if (t < 128) W1[t] = w1[t];
  if (t < 16) { B1[t] = b1[t]; W2[t] = w2[t]; }
  for (int i = t; i < NUSED; i += 256) cur[i] = cursor[i * NBLK + blk];
  __syncthreads();
  const int s = blk * EPB, e = s + EPB;
  for (int j = s + t; j < e; j += 256) {
    const float4* ap = (const float4*)(ea + (size_t)j * 8);
    float4 a0 = ap[0], a1 = ap[1];
    float a[8] = {a0.x, a0.y, a0.z, a0.w, a1.x, a1.y, a1.z, a1.w};
    float out = b2[0];
#pragma unroll
    for (int i = 0; i < 16; ++i) {
      float h = B1[i];
#pragma unroll
      for (int jj = 0; jj < 8; ++jj) h += a[jj] * W1[i * 8 + jj];
      out += fmaxf(h, 0.f) * W2[i];
    }
    int d = tgt[j];
    int bin = d >> 7;
    int pos = atomicAdd(&cur[bin], 1);
    union { float f; unsigned u; } w;
    w.f = out;
    mb[pos] = make_uint2(w.u, (unsigned)src[j] | ((unsigned)(d & 127) << 25));
  }
}

// ---------------------------------------------------------------------------
// Bucket -> CSR + dinv + x-convert: one block per bucket (=128 nodes).
// ---------------------------------------------------------------------------
__global__ __launch_bounds__(256) void k_csr(
    const uint2* __restrict__ mb, const int* __restrict__ bbase,
    const float* __restrict__ x, uint2* __restrict__ meta,
    int* __restrict__ rowstart, float* __restrict__ dinv,
    unsigned* __restrict__ xb) {
  __shared__ int hist[128];
  __shared__ float degf[128];
  __shared__ int cur[128];
  __shared__ float dls[128];
  const int b = blockIdx.x;
  const int t = threadIdx.x;
  const int s = bbase[b], e = bbase[b + 1];
  if (t < 128) { hist[t] = 0; degf[t] = 0.f; }
  __syncthreads();
  for (int j = s + t; j < e; j += 256) {
    uint2 m = mb[j];
    int bin = m.y >> 25;
    atomicAdd(&hist[bin], 1);
    union { unsigned u; float f; } w;
    w.u = m.x;
    atomicAdd(&degf[bin], w.f);
  }
  __syncthreads();
  int own = (t < 128) ? hist[t] : 0;
  for (int off = 1; off < 128; off <<= 1) {
    int u = (t >= off && t < 128) ? hist[t - off] : 0;
    __syncthreads();
    if (t < 128) hist[t] += u;
    __syncthreads();
  }
  if (t < 128) {
    int excl = hist[t] - own;
    int node = b * 128 + t;
    if (node <= N_NODES) rowstart[node] = s + excl;
    float dv = 0.f;
    if (node < N_NODES) {
      float d = 1.f + degf[t];
      dv = d > 0.f ? rsqrtf(d) : 0.f;
      dinv[node] = dv;
    }
    dls[t] = dv;
    cur[t] = s + excl;
  }
  __syncthreads();
  for (int j = s + t; j < e; j += 256) {
    uint2 m = mb[j];
    int bin = m.y >> 25;
    int pos = atomicAdd(&cur[bin], 1);
    meta[pos] = make_uint2(m.x, m.y & 0x1FFFFFFu);
  }
  // x -> bf16(dinv*x) for this block's 128 nodes (64 ch each)
  {
    const int ln = t >> 1, half = t & 1;
    const int node = b * 128 + ln;
    if (node < N_NODES) {
      float dv = dls[ln];
      const float* px = x + (size_t)node * 64 + half * 32;
#pragma unroll
      for (int c8 = 0; c8 < 4; ++c8) {
        float4 a = *(const float4*)(px + c8 * 8);
        float4 bb = *(const float4*)(px + c8 * 8 + 4);
        uint4 o;
        o.x = packbf(dv * a.x, dv * a.y);
        o.y = packbf(dv * a.z, dv * a.w);
        o.z = packbf(dv * bb.x, dv * bb.y);
        o.w = packbf(dv * bb.z, dv * bb.w);
        *(uint4*)&xb[(size_t)node * 32 + half * 16 + c8 * 4] = o;
      }
    }
  }
}

// ---------------------------------------------------------------------------
// FUSED layer-0: 64-ch gather (on bf16 x' = dinv*x) straight into the MFMA
// A-tile in LDS, then h1b = bf16( A @ W0 + b0 ).
// Block = 64 nodes, 4 waves; wave wv gathers nodes wv*16..+15 sequentially.
// ---------------------------------------------------------------------------
__global__ __launch_bounds__(256) void k_l0(
    const unsigned* __restrict__ xb, const uint2* __restrict__ meta,
    const int* __restrict__ rowstart, const float* __restrict__ dinv,
    const unsigned short* __restrict__ wt0, const float* __restrict__ bias,
    unsigned short* __restrict__ h1b) {
  __shared__ unsigned short Asb[64][72];
  __shared__ unsigned short Wsb[128][72];
  const int t = threadIdx.x;
  const int base = blockIdx.x * 64;

  // stage WT0 (overlaps with gather below across waves)
  for (int i = t; i < 1024; i += 256) {
    int nr = i >> 3, k8 = (i & 7) * 8;
    *(uint4*)&Wsb[nr][k8] = *(const uint4*)&wt0[nr * 64 + k8];
  }

  const int wv = t >> 6;
  const unsigned lane = t & 63;
  const unsigned q = lane >> 3;   // edge slot 0..7
  const unsigned cl = lane & 7;   // uint4 group (8 ch) over 64 ch
  const uint4* x4 = (const uint4*)xb;

  for (int it = 0; it < 16; ++it) {
    const int ln = wv * 16 + it;
    const int n = base + ln;
    if (n >= N_NODES) {
      if (q == 0) {
        uint4 z = make_uint4(0, 0, 0, 0);
        *(uint4*)&Asb[ln][cl * 8] = z;
      }
      continue;
    }
    const int rs = rowstart[n], re = rowstart[n + 1];
    float4 lo0 = make_float4(0.f, 0.f, 0.f, 0.f), hi0 = lo0;
    float4 lo1 = lo0, hi1 = lo0;
    int j = rs;
    for (; j + 16 <= re; j += 16) {
      uint2 m0 = meta[j + q], m1 = meta[j + 8 + q];
      union { unsigned u; float f; } w0, w1;
      w0.u = m0.x; w1.u = m1.x;
      uint4 v0 = x4[(m0.y << 3) + cl];
      uint4 v1 = x4[(m1.y << 3) + cl];
      fma4(lo0, w0.f, bf4(v0.x, v0.y));
      fma4(hi0, w0.f, bf4(v0.z, v0.w));
      fma4(lo1, w1.f, bf4(v1.x, v1.y));
      fma4(hi1, w1.f, bf4(v1.z, v1.w));
    }
    for (; j + 8 <= re; j += 8) {
      uint2 m0 = meta[j + q];
      union { unsigned u; float f; } w0;
      w0.u = m0.x;
      uint4 v0 = x4[(m0.y << 3) + cl];
      fma4(lo0, w0.f, bf4(v0.x, v0.y));
      fma4(hi0, w0.f, bf4(v0.z, v0.w));
    }
    if (j + (int)q < re) {
      uint2 m0 = meta[j + q];
      union { unsigned u; float f; } w0;
      w0.u = m0.x;
      uint4 v0 = x4[(m0.y << 3) + cl];
      fma4(lo1, w0.f, bf4(v0.x, v0.y));
      fma4(hi1, w0.f, bf4(v0.z, v0.w));
    }
    lo0.x += lo1.x; lo0.y += lo1.y; lo0.z += lo1.z; lo0.w += lo1.w;
    hi0.x += hi1.x; hi0.y += hi1.y; hi0.z += hi1.z; hi0.w += hi1.w;
#pragma unroll
    for (int m = 8; m <= 32; m <<= 1) {
      lo0.x += __shfl_xor(lo0.x, m);
      lo0.y += __shfl_xor(lo0.y, m);
      lo0.z += __shfl_xor(lo0.z, m);
      lo0.w += __shfl_xor(lo0.w, m);
      hi0.x += __shfl_xor(hi0.x, m);
      hi0.y += __shfl_xor(hi0.y, m);
      hi0.z += __shfl_xor(hi0.z, m);
      hi0.w += __shfl_xor(hi0.w, m);
    }
    if (q == 0) {
      float dv = dinv[n];
      uint4 sv = x4[((unsigned)n << 3) + cl];
      float4 slo = bf4(sv.x, sv.y), shi = bf4(sv.z, sv.w);
      uint4 o;
      o.x = packbf(dv * (lo0.x + slo.x), dv * (lo0.y + slo.y));
      o.y = packbf(dv * (lo0.z + slo.z), dv * (lo0.w + slo.w));
      o.z = packbf(dv * (hi0.x + shi.x), dv * (hi0.y + shi.y));
      o.w = packbf(dv * (hi0.z + shi.z), dv * (hi0.w + shi.w));
      *(uint4*)&Asb[ln][cl * 8] = o;
    }
  }
  __syncthreads();

  // MFMA: D = Asb @ Wsb^T (+bias) -> h1b
  const int lr = t & 15;
  const int lk = (t >> 4) & 3;
  const int m0 = wv * 16;

  bfrag8 af[2];
#pragma unroll
  for (int kc = 0; kc < 2; ++kc)
    af[kc] = *(const bfrag8*)&Asb[m0 + lr][kc * 32 + lk * 8];

#pragma unroll
  for (int nt = 0; nt < 8; ++nt) {
    facc4 c = {0.f, 0.f, 0.f, 0.f};
#pragma unroll
    for (int kc = 0; kc < 2; ++kc) {
      bfrag8 bf = *(const bfrag8*)&Wsb[nt * 16 + lr][kc * 32 + lk * 8];
      c = __builtin_amdgcn_mfma_f32_16x16x32_bf16(af[kc], bf, c, 0, 0, 0);
    }
    int col = nt * 16 + lr;
    float bv = bias[col];
#pragma unroll
    for (int r = 0; r < 4; ++r) {
      int n = base + m0 + lk * 4 + r;
      if (n < N_NODES) h1b[(size_t)n * 128 + col] = f2bf(c[r] + bv);
    }
  }
}

// ---------------------------------------------------------------------------
// Layers 1-2 MFMA GEMM: hwb = bf16( dinv[n] * (relu(A*h+B) @ W) ).
// ---------------------------------------------------------------------------
__global__ __launch_bounds__(256) void k_hw_mfma(
    const unsigned* __restrict__ hb, const unsigned short* __restrict__ wt,
    const int* __restrict__ batch, const float* __restrict__ An,
    const float* __restrict__ Bn, const float* __restrict__ dinv,
    unsigned short* __restrict__ hwb) {
  __shared__ unsigned short Asb[64][136];
  __shared__ unsigned short Wsb[128][136];
  const int t = threadIdx.x;
  const int base = blockIdx.x * 64;

  for (int i = t; i < 2048; i += 256) {
    int nr = i >> 4, k8 = (i & 15) * 8;
    *(uint4*)&Wsb[nr][k8] = *(const uint4*)&wt[nr * 128 + k8];
  }
  {
    const int ln = t >> 2;
    const int cg = (t & 3) * 32;
    const int n = base + ln;
    if (n < N_NODES) {
      const int g = batch[n];
      const uint4* hp = (const uint4*)(hb + (size_t)n * 64);
      const float* Ap = An + (size_t)g * 128;
      const float* Bp = Bn + (size_t)g * 128;
#pragma unroll
      for (int qq = 0; qq < 4; ++qq) {
        int c = cg + qq * 8;
        uint4 v = hp[(t & 3) * 4 + qq];
        float4 lo = bf4(v.x, v.y);
        float4 hi = bf4(v.z, v.w);
        float4 Alo = *(const float4*)&Ap[c], Blo = *(const float4*)&Bp[c];
        float4 Ahi = *(const float4*)&Ap[c + 4], Bhi = *(const float4*)&Bp[c + 4];
        uint4 o;
        o.x = packbf(fmaxf(Alo.x * lo.x + Blo.x, 0.f),
                     fmaxf(Alo.y * lo.y + Blo.y, 0.f));
        o.y = packbf(fmaxf(Alo.z * lo.z + Blo.z, 0.f),
                     fmaxf(Alo.w * lo.w + Blo.w, 0.f));
        o.z = packbf(fmaxf(Ahi.x * hi.x + Bhi.x, 0.f),
                     fmaxf(Ahi.y * hi.y + Bhi.y, 0.f));
        o.w = packbf(fmaxf(Ahi.z * hi.z + Bhi.z, 0.f),
                     fmaxf(Ahi.w * hi.w + Bhi.w, 0.f));
        *(uint4*)&Asb[ln][c] = o;
      }
    } else {
      uint4 z = make_uint4(0, 0, 0, 0);
#pragma unroll
      for (int qq = 0; qq < 4; ++qq) *(uint4*)&Asb[ln][cg + qq * 8] = z;
    }
  }
  __syncthreads();

  const int wv = t >> 6;
  const int lr = t & 15;
  const int lk = (t >> 4) & 3;
  const int m0 = wv * 16;

  bfrag8 af[4];
#pragma unroll
  for (int kc = 0; kc < 4; ++kc)
    af[kc] = *(const bfrag8*)&Asb[m0 + lr][kc * 32 + lk * 8];

  float dv[4];
#pragma unroll
  for (int r = 0; r < 4; ++r) {
    int n = base + m0 + lk * 4 + r;
    dv[r] = (n < N_NODES) ? dinv[n] : 0.f;
  }

#pragma unroll
  for (int nt = 0; nt < 8; ++nt) {
    facc4 c = {0.f, 0.f, 0.f, 0.f};
#pragma unroll
    for (int kc = 0; kc < 4; ++kc) {
      bfrag8 bf = *(const bfrag8*)&Wsb[nt * 16 + lr][kc * 32 + lk * 8];
      c = __builtin_amdgcn_mfma_f32_16x16x32_bf16(af[kc], bf, c, 0, 0, 0);
    }
    int col = nt * 16 + lr;
#pragma unroll
    for (int r = 0; r < 4; ++r) {
      int n = base + m0 + lk * 4 + r;
      if (n < N_NODES) hwb[(size_t)n * 128 + col] = f2bf(dv[r] * c[r]);
    }
  }
}

// ---------------------------------------------------------------------------
// 128-ch CSR gather on dinv-scaled bf16 table.
// ---------------------------------------------------------------------------
__global__ __launch_bounds__(256) void k_gatherb(
    const unsigned* __restrict__ hwb, const uint2* __restrict__ meta,
    const int* __restrict__ rowstart, const float* __restrict__ dinv,
    const float* __restrict__ bias, unsigned* __restrict__ aggb) {
  const int t = threadIdx.x;
  const int n = blockIdx.x * 4 + (t >> 6);
  if (n >= N_NODES) return;
  const unsigned lane = t & 63;
  const unsigned q = lane >> 4;   // edge slot 0..3
  const unsigned cl = lane & 15;  // uint4 group (8 ch) over 128 ch
  const int rs = rowstart[n], re = rowstart[n + 1];
  const uint4* hb4 = (const uint4*)hwb;
  float4 lo0 = make_float4(0.f, 0.f, 0.f, 0.f), hi0 = lo0;
  float4 lo1 = lo0, hi1 = lo0;
  int j = rs;
  for (; j + 8 <= re; j += 8) {
    uint2 m0 = meta[j + q], m1 = meta[j + 4 + q];
    union { unsigned u; float f; } w0, w1;
    w0.u = m0.x; w1.u = m1.x;
    uint4 v0 = hb4[(m0.y << 4) + cl];
    uint4 v1 = hb4[(m1.y << 4) + cl];
    fma4(lo0, w0.f, bf4(v0.x, v0.y));
    fma4(hi0, w0.f, bf4(v0.z, v0.w));
    fma4(lo1, w1.f, bf4(v1.x, v1.y));
    fma4(hi1, w1.f, bf4(v1.z, v1.w));
  }
  for (; j + 4 <= re; j += 4) {
    uint2 m0 = meta[j + q];
    union { unsigned u; float f; } w0;
    w0.u = m0.x;
    uint4 v0 = hb4[(m0.y << 4) + cl];
    fma4(lo0, w0.f, bf4(v0.x, v0.y));
    fma4(hi0, w0.f, bf4(v0.z, v0.w));
  }
  if (j + (int)q < re) {
    uint2 m0 = meta[j + q];
    union { unsigned u; float f; } w0;
    w0.u = m0.x;
    uint4 v0 = hb4[(m0.y << 4) + cl];
    fma4(lo1, w0.f, bf4(v0.x, v0.y));
    fma4(hi1, w0.f, bf4(v0.z, v0.w));
  }
  lo0.x += lo1.x; lo0.y += lo1.y; lo0.z += lo1.z; lo0.w += lo1.w;
  hi0.x += hi1.x; hi0.y += hi1.y; hi0.z += hi1.z; hi0.w += hi1.w;
#pragma unroll
  for (int m = 16; m <= 32; m <<= 1) {
    lo0.x += __shfl_xor(lo0.x, m);
    lo0.y += __shfl_xor(lo0.y, m);
    lo0.z += __shfl_xor(lo0.z, m);
    lo0.w += __shfl_xor(lo0.w, m);
    hi0.x += __shfl_xor(hi0.x, m);
    hi0.y += __shfl_xor(hi0.y, m);
    hi0.z += __shfl_xor(hi0.z, m);
    hi0.w += __shfl_xor(hi0.w, m);
  }
  if (q == 0) {
    float dv = dinv[n];
    uint4 sv = hb4[((unsigned)n << 4) + cl];
    float4 slo = bf4(sv.x, sv.y), shi = bf4(sv.z, sv.w);
    float4 blo = *(const float4*)&bias[cl * 8];
    float4 bhi = *(const float4*)&bias[cl * 8 + 4];
    uint4 o;
    o.x = packbf(dv * (lo0.x + slo.x) + blo.x, dv * (lo0.y + slo.y) + blo.y);
    o.y = packbf(dv * (lo0.z + slo.z) + blo.z, dv * (lo0.w + slo.w) + blo.w);
    o.z = packbf(dv * (hi0.x + shi.x) + bhi.x, dv * (hi0.y + shi.y) + bhi.y);
    o.w = packbf(dv * (hi0.z + shi.z) + bhi.z, dv * (hi0.w + shi.w) + bhi.w);
    ((uint4*)aggb)[((unsigned)n << 4) + cl] = o;
  }
}

// ---------------------------------------------------------------------------
// GraphNorm stats on bf16 table (layers 0,1).
// ---------------------------------------------------------------------------
__global__ __launch_bounds__(512) void k_gstats(
    const unsigned* __restrict__ hb, const int* __restrict__ start,
    const float* __restrict__ gw, const float* __restrict__ gb,
    const float* __restrict__ gms, float* __restrict__ An,
    float* __restrict__ Bn) {
  int g = blockIdx.x;
  int s = start[g], e = start[g + 1];
  int t = threadIdx.x, p = t >> 7, c = t & 127;
  float sum = 0.f, sq = 0.f;
  for (int n = s + p; n < e; n += 4) {
    float v = bfat(hb + (size_t)n * 64, c);
    sum += v;
    sq += v * v;
  }
  __shared__ float S[4][128], Q[4][128];
  S[p][c] = sum;
  Q[p][c] = sq;
  __syncthreads();
  if (t < 128) {
    float cnt = (float)max(e - s, 1);
    float mean = (S[0][t] + S[1][t] + S[2][t] + S[3][t]) / cnt;
    float e2 = (Q[0][t] + Q[1][t] + Q[2][t] + Q[3][t]) / cnt;
    float ms = gms[t];
    float var = fmaxf(e2 - ms * (2.f - ms) * mean * mean, 0.f);
    float scale = gw[t] / sqrtf(var + EPS);
    An[(size_t)g * 128 + t] = scale;
    Bn[(size_t)g * 128 + t] = gb[t] - scale * ms * mean;
  }
}

// ---------------------------------------------------------------------------
// Layer-2 GraphNorm stats + fused mean-pool of relu(A*h+B).
// ---------------------------------------------------------------------------
__global__ __launch_bounds__(512) void k_gstats_pool(
    const unsigned* __restrict__ hb, const int* __restrict__ start,
    const float* __restrict__ gw, const float* __restrict__ gb,
    const float* __restrict__ gms, float* __restrict__ pooled) {
  int g = blockIdx.x;
  int s = start[g], e = start[g + 1];
  int t = threadIdx.x, p = t >> 7, c = t & 127;
  float sum = 0.f, sq = 0.f;
  for (int n = s + p; n < e; n += 4) {
    float v = bfat(hb + (size_t)n * 64, c);
    sum += v;
    sq += v * v;
  }
  __shared__ float S[4][128], Q[4][128], Af[128], Bf[128];
  S[p][c] = sum;
  Q[p][c] = sq;
  __syncthreads();
  if (t < 128) {
    float cnt = (float)max(e - s, 1);
    float mean = (S[0][t] + S[1][t] + S[2][t] + S[3][t]) / cnt;
    float e2 = (Q[0][t] + Q[1][t] + Q[2][t] + Q[3][t]) / cnt;
    float ms = gms[t];
    float var = fmaxf(e2 - ms * (2.f - ms) * mean * mean, 0.f);
    float scale = gw[t] / sqrtf(var + EPS);
    Af[t] = scale;
    Bf[t] = gb[t] - scale * ms * mean;
  }
  __syncthreads();
  float A = Af[c], B = Bf[c];
  float psum = 0.f;
  for (int n = s + p; n < e; n += 4)
    psum += fmaxf(A * bfat(hb + (size_t)n * 64, c) + B, 0.f);
  __syncthreads();
  S[p][c] = psum;
  __syncthreads();
  if (t < 128) {
    float cnt = (float)max(e - s, 1);
    pooled[g * 128 + t] = (S[0][t] + S[1][t] + S[2][t] + S[3][t]) / cnt;
  }
}

// MLP head: 128 ->256 (BN,ReLU) ->128 (BN,ReLU) ->1; writes out[g] and h2.
__global__ __launch_bounds__(256) void k_head(
    const float* __restrict__ pooled, const float* __restrict__ w0,
    const float* __restrict__ b0, const float* __restrict__ g0,
    const float* __restrict__ bb0, const float* __restrict__ w1,
    const float* __restrict__ b1, const float* __restrict__ g1,
    const float* __restrict__ bb1, const float* __restrict__ ow,
    const float* __restrict__ ob, float* __restrict__ out) {
  __shared__ float p[128], h1[256], h2[128];
  int g = blockIdx.x, t = threadIdx.x;
  const float inv = 1.0f / sqrtf(1.0f + EPS);
  if (t < 128) p[t] = pooled[g * 128 + t];
  __syncthreads();
  {
    float acc = b0[t];
#pragma unroll 8
    for (int k = 0; k < 128; ++k) acc += p[k] * w0[k * 256 + t];
    h1[t] = fmaxf(acc * inv * g0[t] + bb0[t], 0.f);
  }
  __syncthreads();
  if (t < 128) {
    float acc = b1[t];
#pragma unroll 8
    for (int k = 0; k < 256; ++k) acc += h1[k] * w1[k * 128 + t];
    float v = fmaxf(acc * inv * g1[t] + bb1[t], 0.f);
    h2[t] = v;
    out[N_GRAPHS + g * 128 + t] = v;
  }
  __syncthreads();
  if (t < 64) {
    float v = h2[t] * ow[t] + h2[t + 64] * ow[t + 64];
#pragma unroll
    for (int off = 32; off; off >>= 1) v += __shfl_down(v, off);
    if (t == 0) out[g] = v + ob[0];
  }
}

// ---------------------------------------------------------------------------
extern "C" void kernel_launch(void* const* d_in, const int* in_sizes, int n_in,
                              void* d_out, int out_size, void* d_ws,
                              size_t ws_size, hipStream_t stream) {
  const float* x = (const float*)d_in[0];
  const float* edge_attr = (const float*)d_in[1];
  const float* em_w1 = (const float*)d_in[2];
  const float* em_b1 = (const float*)d_in[3];
  const float* em_w2 = (const float*)d_in[4];
  const float* em_b2 = (const float*)d_in[5];
  const float* conv_w[3] = {(const float*)d_in[6], (const float*)d_in[8],
                            (const float*)d_in[10]};
  const float* conv_b[3] = {(const float*)d_in[7], (const float*)d_in[9],
                            (const float*)d_in[11]};
  const float* gn_w[3] = {(const float*)d_in[12], (const float*)d_in[15],
                          (const float*)d_in[18]};
  const float* gn_b[3] = {(const float*)d_in[13], (const float*)d_in[16],
                          (const float*)d_in[19]};
  const float* gn_ms[3] = {(const float*)d_in[14], (const float*)d_in[17],
                           (const float*)d_in[20]};
  const float* lin_w0 = (const float*)d_in[21];
  const float* lin_b0 = (const float*)d_in[22];
  const float* bn_g0 = (const float*)d_in[23];
  const float* bn_b0 = (const float*)d_in[24];
  const float* lin_w1 = (const float*)d_in[25];
  const float* lin_b1 = (const float*)d_in[26];
  const float* bn_g1 = (const float*)d_in[27];
  const float* bn_b1 = (const float*)d_in[28];
  const float* out_w = (const float*)d_in[29];
  const float* out_b = (const float*)d_in[30];
  const int* edge_index = (const int*)d_in[31];
  const int* batch = (const int*)d_in[32];
  const int* src = edge_index;
  const int* tgt = edge_index + N_EDGES;

  char* w = (char*)d_ws;
  size_t off = 0;
  auto carve = [&](size_t bytes) {
    void* p = w + off;
    off = (off + bytes + 511) & ~(size_t)511;
    return p;
  };
  float* dinv = (float*)carve((size_t)N_NODES * 4);
  int* rowstart = (int*)carve((size_t)(N_NODES + 1) * 4);
  int* hists = (int*)carve((size_t)NBLK * NBUCK * 4);
  int* cursor = (int*)carve((size_t)NBUCK * NBLK * 4);
  int* bcnt = (int*)carve((size_t)NBUCK * 4);
  int* bbase = (int*)carve((size_t)(NBUCK + 1) * 4);
  uint2* mb = (uint2*)carve((size_t)N_EDGES * 8);
  uint2* meta = (uint2*)carve((size_t)N_EDGES * 8);
  int* start = (int*)carve((N_GRAPHS + 1) * 4);
  float* AB = (float*)carve((size_t)4 * N_GRAPHS * 128 * 4);
  unsigned* xb = (unsigned*)carve((size_t)N_NODES * 64 * 2);
  unsigned* h1b = (unsigned*)carve((size_t)N_NODES * 128 * 2);
  unsigned* hwb = (unsigned*)carve((size_t)N_NODES * 128 * 2);
  unsigned* agg1b = (unsigned*)carve((size_t)N_NODES * 128 * 2);
  unsigned* agg2b = (unsigned*)carve((size_t)N_NODES * 128 * 2);
  unsigned short* wt0 = (unsigned short*)carve((size_t)128 * 64 * 2);
  unsigned short* wt1 = (unsigned short*)carve((size_t)128 * 128 * 2);
  unsigned short* wt2 = (unsigned short*)carve((size_t)128 * 128 * 2);
  float* pooled = (float*)carve((size_t)N_GRAPHS * 128 * 4);

  float* A0 = AB, *B0 = AB + N_GRAPHS * 128;
  float* A1 = AB + 2 * N_GRAPHS * 128, *B1 = AB + 3 * N_GRAPHS * 128;

  hipMemsetAsync(bcnt, 0, (size_t)NBUCK * 4, stream);

  k_prep<<<PREP_BLOCKS, 256, 0, stream>>>(conv_w[1], conv_w[2], wt1, wt2,
                                          conv_w[0], wt0, batch, start, tgt,
                                          hists, bcnt);
  k_bscan<<<1, 1024, 0, stream>>>(bcnt, bbase);
  k_cursors<<<NUSED, NBLK, 0, stream>>>(hists, bbase, cursor);
  k_scatter<<<NBLK, 256, 0, stream>>>(edge_attr, em_w1, em_b1, em_w2, em_b2,
                                      src, tgt, cursor, mb);
  k_csr<<<NUSED, 256, 0, stream>>>(mb, bbase, x, meta, rowstart, dinv, xb);

  const int ggrid = (N_NODES + 3) / 4;
  const int hwgrid = (N_NODES + 63) / 64;

  // layer 0: FUSED gather64 + MFMA GEMM (+bias) -> h1b.
  k_l0<<<hwgrid, 256, 0, stream>>>(xb, meta, rowstart, dinv, wt0, conv_b[0],
                                   (unsigned short*)h1b);
  k_gstats<<<N_GRAPHS, 512, 0, stream>>>(h1b, start, gn_w[0], gn_b[0],
                                         gn_ms[0], A0, B0);
  // layer 1
  k_hw_mfma<<<hwgrid, 256, 0, stream>>>(h1b, wt1, batch, A0, B0, dinv,
                                        (unsigned short*)hwb);
  k_gatherb<<<ggrid, 256, 0, stream>>>(hwb, meta, rowstart, dinv, conv_b[1],
                                       agg1b);
  k_gstats<<<N_GRAPHS, 512, 0, stream>>>(agg1b, start, gn_w[1], gn_b[1],
                                         gn_ms[1], A1, B1);
  // layer 2
  k_hw_mfma<<<hwgrid, 256, 0, stream>>>(agg1b, wt2, batch, A1, B1, dinv,
                                        (unsigned short*)hwb);
  k_gatherb<<<ggrid, 256, 0, stream>>>(hwb, meta, rowstart, dinv, conv_b[2],
                                       agg2b);
  k_gstats_pool<<<N_GRAPHS, 512, 0, stream>>>(agg2b, start, gn_w[2], gn_b[2],
                                              gn_ms[2], pooled);

  k_head<<<N_GRAPHS, 256, 0, stream>>>(pooled, lin_w0, lin_b0, bn_g0, bn_b0,
                                       lin_w1, lin_b1, bn_g1, bn_b1, out_w,
                                       out_b, (float*)d_out);
}